// Round 4
// baseline (7300.097 us; speedup 1.0000x reference)
//
#include <hip/hip_runtime.h>
#include <cstdint>
#include <cstddef>

// HGT forward (2 layers) on MI355X. fp32 everywhere except v' edge messages
// stored bf16 (error budget analyzed: ~5e-5 at output vs 1.35e-3 threshold).
// Workspace requirement: ~265 MB.

namespace {

constexpr int T_N  = 3;    // node types
constexpr int R_N  = 4;    // relations
constexpr int HD   = 128;  // hidden
constexpr int IND  = 256;  // in_dim
constexpr int NH   = 8;    // heads
constexpr int MAXT = 240;  // RTE table length

typedef unsigned short u16;
typedef unsigned int   u32;

__device__ __forceinline__ u16 f2bf(float f) {        // round-to-nearest-even
  u32 u = __float_as_uint(f);
  u += 0x7fffu + ((u >> 16) & 1u);
  return (u16)(u >> 16);
}

// ----------------------------- utility kernels -----------------------------
__global__ void k_fill_i32(int* __restrict__ p, int v, int n) {
  int i = blockIdx.x * 256 + threadIdx.x;
  if (i < n) p[i] = v;
}
__global__ void k_copy_i32(int* __restrict__ d, const int* __restrict__ s, int n) {
  int i = blockIdx.x * 256 + threadIdx.x;
  if (i < n) d[i] = s[i];
}
__global__ void k_hist_dst(const int* __restrict__ dst, int* __restrict__ cnt, int E) {
  int i = blockIdx.x * 256 + threadIdx.x;
  if (i < E) atomicAdd(&cnt[dst[i]], 1);
}
// exclusive scan, 3-kernel (block=256). nb must be <= 256 (N=50001 -> 196).
__global__ void k_scan_a(const int* __restrict__ in, int* __restrict__ out,
                         int* __restrict__ bsums, int n) {
  __shared__ int s[256];
  int gid = blockIdx.x * 256 + threadIdx.x;
  int v = (gid < n) ? in[gid] : 0;
  s[threadIdx.x] = v;
  __syncthreads();
  for (int off = 1; off < 256; off <<= 1) {
    int t = (threadIdx.x >= off) ? s[threadIdx.x - off] : 0;
    __syncthreads();
    s[threadIdx.x] += t;
    __syncthreads();
  }
  if (gid < n) out[gid] = s[threadIdx.x] - v;
  if (threadIdx.x == 255) bsums[blockIdx.x] = s[255];
}
__global__ void k_scan_b(int* __restrict__ bsums, int nb) {
  __shared__ int s[256];
  int v = (threadIdx.x < nb) ? bsums[threadIdx.x] : 0;
  s[threadIdx.x] = v;
  __syncthreads();
  for (int off = 1; off < 256; off <<= 1) {
    int t = (threadIdx.x >= off) ? s[threadIdx.x - off] : 0;
    __syncthreads();
    s[threadIdx.x] += t;
    __syncthreads();
  }
  if (threadIdx.x < nb) bsums[threadIdx.x] = s[threadIdx.x] - v;
}
__global__ void k_scan_c(int* __restrict__ out, const int* __restrict__ bsums, int n) {
  int gid = blockIdx.x * 256 + threadIdx.x;
  if (gid < n) out[gid] += bsums[blockIdx.x];
}
__global__ void k_scatter_dst(const int* __restrict__ dst, int* __restrict__ cur,
                              int* __restrict__ eids, int E) {
  int i = blockIdx.x * 256 + threadIdx.x;
  if (i < E) {
    int pos = atomicAdd(&cur[dst[i]], 1);
    eids[pos] = i;
  }
}
// 12-bucket (src_type, rel_type) histogram / aligned offsets / scatter
__global__ void k_bhist(const int* __restrict__ src, const int* __restrict__ etype,
                        const int* __restrict__ ntype, int* __restrict__ bcnt, int E) {
  __shared__ int loc[12];
  if (threadIdx.x < 12) loc[threadIdx.x] = 0;
  __syncthreads();
  int i = blockIdx.x * 256 + threadIdx.x;
  if (i < E) {
    int b = ntype[src[i]] * R_N + etype[i];
    atomicAdd(&loc[b], 1);
  }
  __syncthreads();
  if (threadIdx.x < 12) atomicAdd(&bcnt[threadIdx.x], loc[threadIdx.x]);
}
__global__ void k_bscan(const int* __restrict__ bcnt, int* __restrict__ bal,
                        int* __restrict__ bcur) {
  if (threadIdx.x == 0 && blockIdx.x == 0) {
    int run = 0;
    for (int b = 0; b < 12; b++) {
      bal[b] = run;
      bcur[b] = run;
      run += (bcnt[b] + 63) & ~63;   // 64-align each bucket region
    }
    bal[12] = run;
  }
}
__global__ void k_bscatter(const int* __restrict__ src, const int* __restrict__ etype,
                           const int* __restrict__ ntype, int* __restrict__ bcur,
                           int* __restrict__ esorted, int E) {
  int i = blockIdx.x * 256 + threadIdx.x;
  if (i < E) {
    int b = ntype[src[i]] * R_N + etype[i];
    int pos = atomicAdd(&bcur[b], 1);
    esorted[pos] = i;
  }
}

// ------------------------------ math kernels -------------------------------
// adapt: x[n] = tanh(node_feature[n] @ adapt_W[t] + adapt_b[t]); 1 wave/node
__global__ void k_adapt(const float* __restrict__ nf, const int* __restrict__ nt,
                        const float* __restrict__ W, const float* __restrict__ b,
                        float* __restrict__ x, int N) {
  int n = blockIdx.x;
  int lane = threadIdx.x;
  __shared__ __align__(16) float s[IND];
  ((float4*)s)[lane] = ((const float4*)(nf + (size_t)n * IND))[lane];  // 64*16B = 256 f
  __syncthreads();
  int t = nt[n];
  const float* Wt = W + (size_t)t * IND * HD;
  float o0 = b[t * HD + 2 * lane];
  float o1 = b[t * HD + 2 * lane + 1];
  #pragma unroll 4
  for (int k = 0; k < IND; k++) {
    float xv = s[k];
    float2 w = ((const float2*)(Wt + (size_t)k * HD))[lane];
    o0 = fmaf(xv, w.x, o0);
    o1 = fmaf(xv, w.y, o1);
  }
  x[(size_t)n * HD + 2 * lane]     = tanhf(o0);
  x[(size_t)n * HD + 2 * lane + 1] = tanhf(o1);
}

// rte_table[t] = rte_emb[t] @ rte_W[l] + rte_b[l]; 240 waves
__global__ void k_rte(const float* __restrict__ emb, const float* __restrict__ W,
                      const float* __restrict__ bias, float* __restrict__ out, int l) {
  int t = blockIdx.x;
  int lane = threadIdx.x;
  __shared__ __align__(16) float s[2 * HD];
  ((float4*)s)[lane] = ((const float4*)(emb + (size_t)t * 2 * HD))[lane];
  __syncthreads();
  const float* Wl = W + (size_t)l * 2 * HD * HD;
  float o0 = bias[l * HD + 2 * lane];
  float o1 = bias[l * HD + 2 * lane + 1];
  #pragma unroll 4
  for (int k = 0; k < 2 * HD; k++) {
    float xv = s[k];
    float2 w = ((const float2*)(Wl + (size_t)k * HD))[lane];
    o0 = fmaf(xv, w.x, o0);
    o1 = fmaf(xv, w.y, o1);
  }
  out[t * HD + 2 * lane]     = o0;
  out[t * HD + 2 * lane + 1] = o1;
}

// q_nodes[n] = x[n] @ Wq[l,t] + bq[l,t]; 1 wave/node
__global__ void k_qnodes(const float* __restrict__ x, const int* __restrict__ nt,
                         const float* __restrict__ Wq_l, const float* __restrict__ bq_l,
                         float* __restrict__ q, int N) {
  int n = blockIdx.x;
  int lane = threadIdx.x;
  __shared__ __align__(16) float s[HD];
  ((float2*)s)[lane] = ((const float2*)(x + (size_t)n * HD))[lane];
  __syncthreads();
  int t = nt[n];
  const float* Wt = Wq_l + (size_t)t * HD * HD;
  float o0 = bq_l[t * HD + 2 * lane];
  float o1 = bq_l[t * HD + 2 * lane + 1];
  #pragma unroll 4
  for (int k = 0; k < HD; k++) {
    float xv = s[k];
    float2 w = ((const float2*)(Wt + (size_t)k * HD))[lane];
    o0 = fmaf(xv, w.x, o0);
    o1 = fmaf(xv, w.y, o1);
  }
  q[(size_t)n * HD + 2 * lane]     = o0;
  q[(size_t)n * HD + 2 * lane + 1] = o1;
}

// Combined per-(type,rel) projection matrices, stored TRANSPOSED [b][c][k]:
//   c <  128: Wcomb[b][c][k] = sum_d Wk[l,st,k,h*16+d] * rel_att[l,rt,h,d,cc]
//   c >= 128: same with Wv / rel_msg.  bcomb analogous from bk/bv.
__global__ void k_wcomb(const float* __restrict__ Wk, const float* __restrict__ Wv,
                        const float* __restrict__ bk, const float* __restrict__ bv,
                        const float* __restrict__ Ratt, const float* __restrict__ Rmsg,
                        float* __restrict__ Wcomb, float* __restrict__ bcomb, int l) {
  int bc = blockIdx.x;          // 12*256 blocks
  int b  = bc >> 8;
  int c  = bc & 255;
  int st = b >> 2, rt = b & 3;
  int k  = threadIdx.x;         // 128 threads
  bool isv = (c >= HD);
  int c0 = isv ? c - HD : c;
  int h  = c0 >> 4, cc = c0 & 15;
  const float* W = (isv ? Wv : Wk) + (((size_t)(l * T_N + st) * HD) + k) * HD + h * 16;
  const float* A = (isv ? Rmsg : Ratt) + (((size_t)(l * R_N + rt) * NH + h) * 16) * 16 + cc;
  float s = 0.f;
  #pragma unroll
  for (int d = 0; d < 16; d++) s = fmaf(W[d], A[d * 16], s);
  Wcomb[((size_t)b * 256 + c) * HD + k] = s;
  if (k == 0) {
    const float* bb = (isv ? bv : bk) + (size_t)(l * T_N + st) * HD + h * 16;
    float sb = 0.f;
    #pragma unroll
    for (int d = 0; d < 16; d++) sb = fmaf(bb[d], A[d * 16], sb);
    bcomb[b * 256 + c] = sb;
  }
}

// Heavy kernel: per 64-edge tile of one (st,rt) bucket:
//   src_vec = x[src]+rte  ->  k' (128) & v' (128) via combined GEMM,
//   score[e][h] = (q[dst]_h . k'_h) * pri * 0.25,  v' -> bf16 global.
__global__ __launch_bounds__(256) void k_edge_gemm(
    const float* __restrict__ x, const float* __restrict__ rte_t,
    const float* __restrict__ Wcomb, const float* __restrict__ bcomb,
    const float* __restrict__ q_nodes, const int* __restrict__ esorted,
    const int* __restrict__ bal, const int* __restrict__ src,
    const int* __restrict__ dst, const int* __restrict__ etime,
    const int* __restrict__ ntype, const float* __restrict__ pri_l,
    float* __restrict__ score, u16* __restrict__ v_e) {
  int tile0 = blockIdx.x * 64;
  if (tile0 >= bal[12]) return;
  int b = 0;
  #pragma unroll
  for (int i = 1; i < 12; i++) b += (tile0 >= bal[i]);
  int st = b >> 2, rt = b & 3;

  __shared__ __align__(16) float sv[64][HD];   // 32 KB; src_vec then reused for k'
  __shared__ int s_eid[64];
  __shared__ int s_dst[64];
  int tid = threadIdx.x;

  if (tid < 64) {
    int e = esorted[tile0 + tid];
    s_eid[tid] = e;
    s_dst[tid] = (e >= 0) ? dst[e] : 0;
  }
  __syncthreads();

  { // stage src_vec: thread -> (row = tid>>2, quarter = tid&3), 8x float4 each
    int r = tid >> 2, p = tid & 3;
    int e = s_eid[r];
    float4* dp = (float4*)(&sv[r][p * 32]);
    if (e >= 0) {
      const float4* xs = (const float4*)(x + (size_t)src[e] * HD + p * 32);
      const float4* rp = (const float4*)(rte_t + (size_t)etime[e] * HD + p * 32);
      #pragma unroll
      for (int i = 0; i < 8; i++) {
        float4 a = xs[i], c = rp[i];
        a.x += c.x; a.y += c.y; a.z += c.z; a.w += c.w;
        dp[i] = a;
      }
    } else {
      #pragma unroll
      for (int i = 0; i < 8; i++) dp[i] = float4{0.f, 0.f, 0.f, 0.f};
    }
  }
  __syncthreads();

  // register-blocked GEMM: thread owns 8 edges x 8 cols (cols c = cg + 32j;
  // j<4 -> k', j>=4 -> v'). All acc indices compile-time (no scratch).
  int cg = tid & 31, eg = tid >> 5;
  float acc[8][8];
  #pragma unroll
  for (int j = 0; j < 8; j++) {
    float bc = bcomb[b * 256 + cg + 32 * j];
    #pragma unroll
    for (int i = 0; i < 8; i++) acc[i][j] = bc;
  }
  const float* W = Wcomb + (size_t)b * 256 * HD;  // [c][k]
  for (int kk = 0; kk < HD; kk += 4) {
    float4 w[8];
    #pragma unroll
    for (int j = 0; j < 8; j++)
      w[j] = *(const float4*)(W + (size_t)(cg + 32 * j) * HD + kk);
    #pragma unroll
    for (int i = 0; i < 8; i++) {
      float4 s4 = *(const float4*)(&sv[eg * 8 + i][kk]);  // 2-addr broadcast: free
      #pragma unroll
      for (int j = 0; j < 8; j++)
        acc[i][j] = fmaf(s4.x, w[j].x,
                    fmaf(s4.y, w[j].y,
                    fmaf(s4.z, w[j].z,
                    fmaf(s4.w, w[j].w, acc[i][j]))));
    }
  }

  // v' -> bf16 global (cols j>=4 are v-cols c-128 = cg+32*(j-4))
  #pragma unroll
  for (int i = 0; i < 8; i++) {
    int e = s_eid[eg * 8 + i];
    if (e >= 0) {
      u16* vp = v_e + (size_t)e * HD;
      #pragma unroll
      for (int j = 0; j < 4; j++) vp[cg + 32 * j] = f2bf(acc[i][4 + j]);
    }
  }
  __syncthreads();                 // everyone done reading sv
  #pragma unroll
  for (int i = 0; i < 8; i++) {    // k' into LDS (reuse sv)
    #pragma unroll
    for (int j = 0; j < 4; j++) sv[eg * 8 + i][cg + 32 * j] = acc[i][j];
  }
  __syncthreads();

  // scores: 512 (edge, head) pairs over 256 threads
  #pragma unroll
  for (int s = 0; s < 2; s++) {
    int p = tid + 256 * s;
    int e = p >> 3, h = p & 7;
    int eid = s_eid[e];
    if (eid >= 0) {
      int d = s_dst[e];
      int tt = ntype[d];
      const float*  kp = &sv[e][h * 16];
      const float4* qp = (const float4*)(q_nodes + (size_t)d * HD + h * 16);
      float sc = 0.f;
      #pragma unroll
      for (int q4 = 0; q4 < 4; q4++) {
        float4 qv = qp[q4];
        sc += qv.x * kp[q4 * 4]     + qv.y * kp[q4 * 4 + 1]
            + qv.z * kp[q4 * 4 + 2] + qv.w * kp[q4 * 4 + 3];
      }
      float pri = pri_l[((tt * R_N + rt) * T_N + st) * NH + h];
      score[(size_t)eid * NH + h] = sc * pri * 0.25f;  // 1/sqrt(16)
    }
  }
}

// Per-node (1 wave): segment softmax over incoming edges, weighted v-sum,
// exact GELU, per-type output linear, sigmoid-skip blend IN PLACE in x.
__global__ void k_aggr(const int* __restrict__ row_ptr, const int* __restrict__ eids,
                       const float* __restrict__ score, const u16* __restrict__ v_e,
                       const int* __restrict__ ntype, const float* __restrict__ Wa_l,
                       const float* __restrict__ ba_l, const float* __restrict__ skip_l,
                       float* __restrict__ x, int N) {
  int n = blockIdx.x;
  int lane = threadIdx.x;
  int start = row_ptr[n], end = row_ptr[n + 1];

  // pass 1: per-head max & sum(exp). lane = (jj<<3)|h, 8 lanes per head.
  int h = lane & 7, jj = lane >> 3;
  float m = -3.0e38f;
  for (int idx = start + jj; idx < end; idx += 8) {
    int e = eids[idx];
    m = fmaxf(m, score[(size_t)e * NH + h]);
  }
  #pragma unroll
  for (int off = 8; off < 64; off <<= 1) m = fmaxf(m, __shfl_xor(m, off));
  float z = 0.f;
  for (int idx = start + jj; idx < end; idx += 8) {
    int e = eids[idx];
    z += expf(score[(size_t)e * NH + h] - m);
  }
  #pragma unroll
  for (int off = 8; off < 64; off <<= 1) z += __shfl_xor(z, off);

  // redistribute to dim layout: lane owns dims {2*lane, 2*lane+1}, head = lane>>3
  int myh = lane >> 3;
  float md = __shfl(m, myh);
  float zd = __shfl(z, myh);
  float rz = (zd > 0.f) ? 1.f / zd : 0.f;

  // pass 2: weighted sum of v'
  float a0 = 0.f, a1 = 0.f;
  for (int idx = start; idx < end; idx++) {
    int e = eids[idx];
    float w = expf(score[(size_t)e * NH + myh] - md) * rz;
    u32 v2 = ((const u32*)(v_e + (size_t)e * HD))[lane];
    float v0 = __uint_as_float((v2 & 0xffffu) << 16);
    float v1 = __uint_as_float((v2 >> 16) << 16);
    a0 = fmaf(w, v0, a0);
    a1 = fmaf(w, v1, a1);
  }

  // exact GELU
  a0 = 0.5f * a0 * (1.f + erff(a0 * 0.7071067811865475f));
  a1 = 0.5f * a1 * (1.f + erff(a1 * 0.7071067811865475f));

  __shared__ __align__(16) float g[HD];
  g[2 * lane]     = a0;
  g[2 * lane + 1] = a1;
  __syncthreads();   // block == 1 wave

  int t = ntype[n];
  const float* Wt = Wa_l + (size_t)t * HD * HD;
  float o0 = ba_l[t * HD + 2 * lane];
  float o1 = ba_l[t * HD + 2 * lane + 1];
  #pragma unroll 4
  for (int k = 0; k < HD; k++) {
    float xv = g[k];
    float2 w = ((const float2*)(Wt + (size_t)k * HD))[lane];
    o0 = fmaf(xv, w.x, o0);
    o1 = fmaf(xv, w.y, o1);
  }
  float alpha = 1.f / (1.f + expf(-skip_l[t]));
  float2 xo = ((const float2*)(x + (size_t)n * HD))[lane];
  float2 xn;
  xn.x = o0 * alpha + xo.x * (1.f - alpha);
  xn.y = o1 * alpha + xo.y * (1.f - alpha);
  ((float2*)(x + (size_t)n * HD))[lane] = xn;
}

}  // namespace

extern "C" void kernel_launch(void* const* d_in, const int* in_sizes, int n_in,
                              void* d_out, int out_size, void* d_ws, size_t ws_size,
                              hipStream_t stream) {
  const float* node_feature = (const float*)d_in[0];
  const int*   node_type    = (const int*)d_in[1];
  const int*   edge_time    = (const int*)d_in[2];
  const int*   edge_type    = (const int*)d_in[3];
  const int*   edge_index   = (const int*)d_in[4];
  const float* adapt_W      = (const float*)d_in[5];
  const float* adapt_b      = (const float*)d_in[6];
  const float* Wk           = (const float*)d_in[7];
  const float* bk           = (const float*)d_in[8];
  const float* Wq           = (const float*)d_in[9];
  const float* bq           = (const float*)d_in[10];
  const float* Wv           = (const float*)d_in[11];
  const float* bv           = (const float*)d_in[12];
  const float* Wa           = (const float*)d_in[13];
  const float* ba           = (const float*)d_in[14];
  const float* rel_pri      = (const float*)d_in[15];
  const float* rel_att      = (const float*)d_in[16];
  const float* rel_msg      = (const float*)d_in[17];
  const float* skip         = (const float*)d_in[18];
  const float* rte_emb      = (const float*)d_in[19];
  const float* rte_W        = (const float*)d_in[20];
  const float* rte_b        = (const float*)d_in[21];

  const int N = in_sizes[1];
  const int E = in_sizes[2];
  const int* src  = edge_index;       // row 0
  const int* dstp = edge_index + E;   // row 1

  float* x = (float*)d_out;           // x lives in d_out; k_aggr updates in place

  // ---- workspace carve (256B aligned) ----
  size_t off = 0;
  auto carve = [&](size_t bytes) -> void* {
    void* p = (char*)d_ws + off;
    off += (bytes + 255) & ~(size_t)255;
    return p;
  };
  float* q_nodes = (float*)carve((size_t)N * HD * 4);
  float* score   = (float*)carve((size_t)E * NH * 4);
  u16*   v_e     = (u16*)  carve((size_t)E * HD * 2);
  float* rte_t   = (float*)carve((size_t)MAXT * HD * 4);
  float* Wcomb   = (float*)carve((size_t)12 * 256 * HD * 4);
  float* bcomb   = (float*)carve((size_t)12 * 256 * 4);
  int*   row_ptr = (int*)  carve((size_t)(N + 1) * 4);
  int*   cnt     = (int*)  carve((size_t)(N + 1) * 4);  // histogram, then cursor
  int*   csr_e   = (int*)  carve((size_t)E * 4);
  int*   bsums   = (int*)  carve(1024 * 4);
  int*   bcnt    = (int*)  carve(16 * 4);
  int*   bal     = (int*)  carve(16 * 4);
  int*   bcur    = (int*)  carve(16 * 4);
  const int EP = E + 12 * 64;
  int*   esorted = (int*)  carve((size_t)EP * 4);
  (void)ws_size; (void)n_in; (void)out_size;  // ~265 MB required

  const int gE  = (E + 255) / 256;
  const int gN1 = (N + 1 + 255) / 256;   // scan blocks (196 <= 256)
  const int gN  = (N + 255) / 256;
  const int gEP = (EP + 255) / 256;
  const int tiles = (EP + 63) / 64;

  // ---- CSR by destination (same for both layers) ----
  k_fill_i32<<<gN1, 256, 0, stream>>>(cnt, 0, N + 1);
  k_hist_dst<<<gE, 256, 0, stream>>>(dstp, cnt, E);
  k_scan_a<<<gN1, 256, 0, stream>>>(cnt, row_ptr, bsums, N + 1);
  k_scan_b<<<1, 256, 0, stream>>>(bsums, gN1);
  k_scan_c<<<gN1, 256, 0, stream>>>(row_ptr, bsums, N + 1);
  k_copy_i32<<<gN, 256, 0, stream>>>(cnt, row_ptr, N);
  k_scatter_dst<<<gE, 256, 0, stream>>>(dstp, cnt, csr_e, E);

  // ---- (src_type, rel_type) buckets, 64-aligned regions ----
  k_fill_i32<<<1, 256, 0, stream>>>(bcnt, 0, 16);
  k_bhist<<<gE, 256, 0, stream>>>(src, edge_type, node_type, bcnt, E);
  k_bscan<<<1, 64, 0, stream>>>(bcnt, bal, bcur);
  k_fill_i32<<<gEP, 256, 0, stream>>>(esorted, -1, EP);
  k_bscatter<<<gE, 256, 0, stream>>>(src, edge_type, node_type, bcur, esorted, E);

  // ---- adapt ----
  k_adapt<<<N, 64, 0, stream>>>(node_feature, node_type, adapt_W, adapt_b, x, N);

  // ---- layers ----
  for (int l = 0; l < 2; l++) {
    k_rte<<<MAXT, 64, 0, stream>>>(rte_emb, rte_W, rte_b, rte_t, l);
    k_wcomb<<<12 * 256, 128, 0, stream>>>(Wk, Wv, bk, bv, rel_att, rel_msg,
                                          Wcomb, bcomb, l);
    k_qnodes<<<N, 64, 0, stream>>>(x, node_type,
                                   Wq + (size_t)l * T_N * HD * HD,
                                   bq + (size_t)l * T_N * HD, q_nodes, N);
    k_edge_gemm<<<tiles, 256, 0, stream>>>(x, rte_t, Wcomb, bcomb, q_nodes,
                                           esorted, bal, src, dstp, edge_time,
                                           node_type,
                                           rel_pri + (size_t)l * T_N * R_N * T_N * NH,
                                           score, v_e);
    k_aggr<<<N, 64, 0, stream>>>(row_ptr, csr_e, score, v_e, node_type,
                                 Wa + (size_t)l * T_N * HD * HD,
                                 ba + (size_t)l * T_N * HD,
                                 skip + (size_t)l * T_N, x, N);
  }
}

// Round 5
// 4591.156 us; speedup vs baseline: 1.5900x; 1.5900x over previous
//
#include <hip/hip_runtime.h>
#include <cstdint>
#include <cstddef>

// HGT forward (2 layers) on MI355X. fp32 everywhere except v' edge messages
// stored bf16 (error budget analyzed: ~5e-5 at output vs 1.35e-3 threshold).
// Workspace requirement: ~265 MB.
//
// R4 change: k_bscatter used 800k device-scope atomics on 12 global counters
// (rocprof: 2.46 ms, 0.15% HBM, 0.01% VALUBusy -> pure atomic serialization).
// Now: per-block LDS histogram + one global atomicAdd per (block,bucket) to
// reserve a range, then conflict-free writes. ~37.5k global atomics total.

namespace {

constexpr int T_N  = 3;    // node types
constexpr int R_N  = 4;    // relations
constexpr int HD   = 128;  // hidden
constexpr int IND  = 256;  // in_dim
constexpr int NH   = 8;    // heads
constexpr int MAXT = 240;  // RTE table length

typedef unsigned short u16;
typedef unsigned int   u32;

__device__ __forceinline__ u16 f2bf(float f) {        // round-to-nearest-even
  u32 u = __float_as_uint(f);
  u += 0x7fffu + ((u >> 16) & 1u);
  return (u16)(u >> 16);
}

// ----------------------------- utility kernels -----------------------------
__global__ void k_fill_i32(int* __restrict__ p, int v, int n) {
  int i = blockIdx.x * 256 + threadIdx.x;
  if (i < n) p[i] = v;
}
__global__ void k_copy_i32(int* __restrict__ d, const int* __restrict__ s, int n) {
  int i = blockIdx.x * 256 + threadIdx.x;
  if (i < n) d[i] = s[i];
}
__global__ void k_hist_dst(const int* __restrict__ dst, int* __restrict__ cnt, int E) {
  int i = blockIdx.x * 256 + threadIdx.x;
  if (i < E) atomicAdd(&cnt[dst[i]], 1);
}
// exclusive scan, 3-kernel (block=256). nb must be <= 256 (N=50001 -> 196).
__global__ void k_scan_a(const int* __restrict__ in, int* __restrict__ out,
                         int* __restrict__ bsums, int n) {
  __shared__ int s[256];
  int gid = blockIdx.x * 256 + threadIdx.x;
  int v = (gid < n) ? in[gid] : 0;
  s[threadIdx.x] = v;
  __syncthreads();
  for (int off = 1; off < 256; off <<= 1) {
    int t = (threadIdx.x >= off) ? s[threadIdx.x - off] : 0;
    __syncthreads();
    s[threadIdx.x] += t;
    __syncthreads();
  }
  if (gid < n) out[gid] = s[threadIdx.x] - v;
  if (threadIdx.x == 255) bsums[blockIdx.x] = s[255];
}
__global__ void k_scan_b(int* __restrict__ bsums, int nb) {
  __shared__ int s[256];
  int v = (threadIdx.x < nb) ? bsums[threadIdx.x] : 0;
  s[threadIdx.x] = v;
  __syncthreads();
  for (int off = 1; off < 256; off <<= 1) {
    int t = (threadIdx.x >= off) ? s[threadIdx.x - off] : 0;
    __syncthreads();
    s[threadIdx.x] += t;
    __syncthreads();
  }
  if (threadIdx.x < nb) bsums[threadIdx.x] = s[threadIdx.x] - v;
}
__global__ void k_scan_c(int* __restrict__ out, const int* __restrict__ bsums, int n) {
  int gid = blockIdx.x * 256 + threadIdx.x;
  if (gid < n) out[gid] += bsums[blockIdx.x];
}
__global__ void k_scatter_dst(const int* __restrict__ dst, int* __restrict__ cur,
                              int* __restrict__ eids, int E) {
  int i = blockIdx.x * 256 + threadIdx.x;
  if (i < E) {
    int pos = atomicAdd(&cur[dst[i]], 1);
    eids[pos] = i;
  }
}
// 12-bucket (src_type, rel_type) histogram / aligned offsets / scatter
__global__ void k_bhist(const int* __restrict__ src, const int* __restrict__ etype,
                        const int* __restrict__ ntype, int* __restrict__ bcnt, int E) {
  __shared__ int loc[12];
  if (threadIdx.x < 12) loc[threadIdx.x] = 0;
  __syncthreads();
  int i = blockIdx.x * 256 + threadIdx.x;
  if (i < E) {
    int b = ntype[src[i]] * R_N + etype[i];
    atomicAdd(&loc[b], 1);
  }
  __syncthreads();
  if (threadIdx.x < 12) atomicAdd(&bcnt[threadIdx.x], loc[threadIdx.x]);
}
__global__ void k_bscan(const int* __restrict__ bcnt, int* __restrict__ bal,
                        int* __restrict__ bcur) {
  if (threadIdx.x == 0 && blockIdx.x == 0) {
    int run = 0;
    for (int b = 0; b < 12; b++) {
      bal[b] = run;
      bcur[b] = run;
      run += (bcnt[b] + 63) & ~63;   // 64-align each bucket region
    }
    bal[12] = run;
  }
}
// R4: per-block LDS histogram; ONE global atomic per (block,bucket) reserves a
// range; edges write at base[b]+local_rank. 800k -> ~37.5k global atomics.
__global__ void k_bscatter(const int* __restrict__ src, const int* __restrict__ etype,
                           const int* __restrict__ ntype, int* __restrict__ bcur,
                           int* __restrict__ esorted, int E) {
  __shared__ int loc[12];
  __shared__ int base[12];
  if (threadIdx.x < 12) loc[threadIdx.x] = 0;
  __syncthreads();
  int i = blockIdx.x * 256 + threadIdx.x;
  int b = 0, lpos = 0;
  if (i < E) {
    b = ntype[src[i]] * R_N + etype[i];
    lpos = atomicAdd(&loc[b], 1);            // LDS atomic: intra-block rank
  }
  __syncthreads();
  if (threadIdx.x < 12) {
    int c = loc[threadIdx.x];
    base[threadIdx.x] = (c > 0) ? atomicAdd(&bcur[threadIdx.x], c) : 0;
  }
  __syncthreads();
  if (i < E) esorted[base[b] + lpos] = i;
}

// ------------------------------ math kernels -------------------------------
// adapt: x[n] = tanh(node_feature[n] @ adapt_W[t] + adapt_b[t]); 1 wave/node
__global__ void k_adapt(const float* __restrict__ nf, const int* __restrict__ nt,
                        const float* __restrict__ W, const float* __restrict__ b,
                        float* __restrict__ x, int N) {
  int n = blockIdx.x;
  int lane = threadIdx.x;
  __shared__ __align__(16) float s[IND];
  ((float4*)s)[lane] = ((const float4*)(nf + (size_t)n * IND))[lane];  // 64*16B = 256 f
  __syncthreads();
  int t = nt[n];
  const float* Wt = W + (size_t)t * IND * HD;
  float o0 = b[t * HD + 2 * lane];
  float o1 = b[t * HD + 2 * lane + 1];
  #pragma unroll 4
  for (int k = 0; k < IND; k++) {
    float xv = s[k];
    float2 w = ((const float2*)(Wt + (size_t)k * HD))[lane];
    o0 = fmaf(xv, w.x, o0);
    o1 = fmaf(xv, w.y, o1);
  }
  x[(size_t)n * HD + 2 * lane]     = tanhf(o0);
  x[(size_t)n * HD + 2 * lane + 1] = tanhf(o1);
}

// rte_table[t] = rte_emb[t] @ rte_W[l] + rte_b[l]; 240 waves
__global__ void k_rte(const float* __restrict__ emb, const float* __restrict__ W,
                      const float* __restrict__ bias, float* __restrict__ out, int l) {
  int t = blockIdx.x;
  int lane = threadIdx.x;
  __shared__ __align__(16) float s[2 * HD];
  ((float4*)s)[lane] = ((const float4*)(emb + (size_t)t * 2 * HD))[lane];
  __syncthreads();
  const float* Wl = W + (size_t)l * 2 * HD * HD;
  float o0 = bias[l * HD + 2 * lane];
  float o1 = bias[l * HD + 2 * lane + 1];
  #pragma unroll 4
  for (int k = 0; k < 2 * HD; k++) {
    float xv = s[k];
    float2 w = ((const float2*)(Wl + (size_t)k * HD))[lane];
    o0 = fmaf(xv, w.x, o0);
    o1 = fmaf(xv, w.y, o1);
  }
  out[t * HD + 2 * lane]     = o0;
  out[t * HD + 2 * lane + 1] = o1;
}

// q_nodes[n] = x[n] @ Wq[l,t] + bq[l,t]; 1 wave/node
__global__ void k_qnodes(const float* __restrict__ x, const int* __restrict__ nt,
                         const float* __restrict__ Wq_l, const float* __restrict__ bq_l,
                         float* __restrict__ q, int N) {
  int n = blockIdx.x;
  int lane = threadIdx.x;
  __shared__ __align__(16) float s[HD];
  ((float2*)s)[lane] = ((const float2*)(x + (size_t)n * HD))[lane];
  __syncthreads();
  int t = nt[n];
  const float* Wt = Wq_l + (size_t)t * HD * HD;
  float o0 = bq_l[t * HD + 2 * lane];
  float o1 = bq_l[t * HD + 2 * lane + 1];
  #pragma unroll 4
  for (int k = 0; k < HD; k++) {
    float xv = s[k];
    float2 w = ((const float2*)(Wt + (size_t)k * HD))[lane];
    o0 = fmaf(xv, w.x, o0);
    o1 = fmaf(xv, w.y, o1);
  }
  q[(size_t)n * HD + 2 * lane]     = o0;
  q[(size_t)n * HD + 2 * lane + 1] = o1;
}

// Combined per-(type,rel) projection matrices, stored TRANSPOSED [b][c][k]:
//   c <  128: Wcomb[b][c][k] = sum_d Wk[l,st,k,h*16+d] * rel_att[l,rt,h,d,cc]
//   c >= 128: same with Wv / rel_msg.  bcomb analogous from bk/bv.
__global__ void k_wcomb(const float* __restrict__ Wk, const float* __restrict__ Wv,
                        const float* __restrict__ bk, const float* __restrict__ bv,
                        const float* __restrict__ Ratt, const float* __restrict__ Rmsg,
                        float* __restrict__ Wcomb, float* __restrict__ bcomb, int l) {
  int bc = blockIdx.x;          // 12*256 blocks
  int b  = bc >> 8;
  int c  = bc & 255;
  int st = b >> 2, rt = b & 3;
  int k  = threadIdx.x;         // 128 threads
  bool isv = (c >= HD);
  int c0 = isv ? c - HD : c;
  int h  = c0 >> 4, cc = c0 & 15;
  const float* W = (isv ? Wv : Wk) + (((size_t)(l * T_N + st) * HD) + k) * HD + h * 16;
  const float* A = (isv ? Rmsg : Ratt) + (((size_t)(l * R_N + rt) * NH + h) * 16) * 16 + cc;
  float s = 0.f;
  #pragma unroll
  for (int d = 0; d < 16; d++) s = fmaf(W[d], A[d * 16], s);
  Wcomb[((size_t)b * 256 + c) * HD + k] = s;
  if (k == 0) {
    const float* bb = (isv ? bv : bk) + (size_t)(l * T_N + st) * HD + h * 16;
    float sb = 0.f;
    #pragma unroll
    for (int d = 0; d < 16; d++) sb = fmaf(bb[d], A[d * 16], sb);
    bcomb[b * 256 + c] = sb;
  }
}

// Heavy kernel: per 64-edge tile of one (st,rt) bucket:
//   src_vec = x[src]+rte  ->  k' (128) & v' (128) via combined GEMM,
//   score[e][h] = (q[dst]_h . k'_h) * pri * 0.25,  v' -> bf16 global.
__global__ __launch_bounds__(256) void k_edge_gemm(
    const float* __restrict__ x, const float* __restrict__ rte_t,
    const float* __restrict__ Wcomb, const float* __restrict__ bcomb,
    const float* __restrict__ q_nodes, const int* __restrict__ esorted,
    const int* __restrict__ bal, const int* __restrict__ src,
    const int* __restrict__ dst, const int* __restrict__ etime,
    const int* __restrict__ ntype, const float* __restrict__ pri_l,
    float* __restrict__ score, u16* __restrict__ v_e) {
  int tile0 = blockIdx.x * 64;
  if (tile0 >= bal[12]) return;
  int b = 0;
  #pragma unroll
  for (int i = 1; i < 12; i++) b += (tile0 >= bal[i]);
  int st = b >> 2, rt = b & 3;

  __shared__ __align__(16) float sv[64][HD];   // 32 KB; src_vec then reused for k'
  __shared__ int s_eid[64];
  __shared__ int s_dst[64];
  int tid = threadIdx.x;

  if (tid < 64) {
    int e = esorted[tile0 + tid];
    s_eid[tid] = e;
    s_dst[tid] = (e >= 0) ? dst[e] : 0;
  }
  __syncthreads();

  { // stage src_vec: thread -> (row = tid>>2, quarter = tid&3), 8x float4 each
    int r = tid >> 2, p = tid & 3;
    int e = s_eid[r];
    float4* dp = (float4*)(&sv[r][p * 32]);
    if (e >= 0) {
      const float4* xs = (const float4*)(x + (size_t)src[e] * HD + p * 32);
      const float4* rp = (const float4*)(rte_t + (size_t)etime[e] * HD + p * 32);
      #pragma unroll
      for (int i = 0; i < 8; i++) {
        float4 a = xs[i], c = rp[i];
        a.x += c.x; a.y += c.y; a.z += c.z; a.w += c.w;
        dp[i] = a;
      }
    } else {
      #pragma unroll
      for (int i = 0; i < 8; i++) dp[i] = float4{0.f, 0.f, 0.f, 0.f};
    }
  }
  __syncthreads();

  // register-blocked GEMM: thread owns 8 edges x 8 cols (cols c = cg + 32j;
  // j<4 -> k', j>=4 -> v'). All acc indices compile-time (no scratch).
  int cg = tid & 31, eg = tid >> 5;
  float acc[8][8];
  #pragma unroll
  for (int j = 0; j < 8; j++) {
    float bc = bcomb[b * 256 + cg + 32 * j];
    #pragma unroll
    for (int i = 0; i < 8; i++) acc[i][j] = bc;
  }
  const float* W = Wcomb + (size_t)b * 256 * HD;  // [c][k]
  for (int kk = 0; kk < HD; kk += 4) {
    float4 w[8];
    #pragma unroll
    for (int j = 0; j < 8; j++)
      w[j] = *(const float4*)(W + (size_t)(cg + 32 * j) * HD + kk);
    #pragma unroll
    for (int i = 0; i < 8; i++) {
      float4 s4 = *(const float4*)(&sv[eg * 8 + i][kk]);  // 2-addr broadcast: free
      #pragma unroll
      for (int j = 0; j < 8; j++)
        acc[i][j] = fmaf(s4.x, w[j].x,
                    fmaf(s4.y, w[j].y,
                    fmaf(s4.z, w[j].z,
                    fmaf(s4.w, w[j].w, acc[i][j]))));
    }
  }

  // v' -> bf16 global (cols j>=4 are v-cols c-128 = cg+32*(j-4))
  #pragma unroll
  for (int i = 0; i < 8; i++) {
    int e = s_eid[eg * 8 + i];
    if (e >= 0) {
      u16* vp = v_e + (size_t)e * HD;
      #pragma unroll
      for (int j = 0; j < 4; j++) vp[cg + 32 * j] = f2bf(acc[i][4 + j]);
    }
  }
  __syncthreads();                 // everyone done reading sv
  #pragma unroll
  for (int i = 0; i < 8; i++) {    // k' into LDS (reuse sv)
    #pragma unroll
    for (int j = 0; j < 4; j++) sv[eg * 8 + i][cg + 32 * j] = acc[i][j];
  }
  __syncthreads();

  // scores: 512 (edge, head) pairs over 256 threads
  #pragma unroll
  for (int s = 0; s < 2; s++) {
    int p = tid + 256 * s;
    int e = p >> 3, h = p & 7;
    int eid = s_eid[e];
    if (eid >= 0) {
      int d = s_dst[e];
      int tt = ntype[d];
      const float*  kp = &sv[e][h * 16];
      const float4* qp = (const float4*)(q_nodes + (size_t)d * HD + h * 16);
      float sc = 0.f;
      #pragma unroll
      for (int q4 = 0; q4 < 4; q4++) {
        float4 qv = qp[q4];
        sc += qv.x * kp[q4 * 4]     + qv.y * kp[q4 * 4 + 1]
            + qv.z * kp[q4 * 4 + 2] + qv.w * kp[q4 * 4 + 3];
      }
      float pri = pri_l[((tt * R_N + rt) * T_N + st) * NH + h];
      score[(size_t)eid * NH + h] = sc * pri * 0.25f;  // 1/sqrt(16)
    }
  }
}

// Per-node (1 wave): segment softmax over incoming edges, weighted v-sum,
// exact GELU, per-type output linear, sigmoid-skip blend IN PLACE in x.
__global__ void k_aggr(const int* __restrict__ row_ptr, const int* __restrict__ eids,
                       const float* __restrict__ score, const u16* __restrict__ v_e,
                       const int* __restrict__ ntype, const float* __restrict__ Wa_l,
                       const float* __restrict__ ba_l, const float* __restrict__ skip_l,
                       float* __restrict__ x, int N) {
  int n = blockIdx.x;
  int lane = threadIdx.x;
  int start = row_ptr[n], end = row_ptr[n + 1];

  // pass 1: per-head max & sum(exp). lane = (jj<<3)|h, 8 lanes per head.
  int h = lane & 7, jj = lane >> 3;
  float m = -3.0e38f;
  for (int idx = start + jj; idx < end; idx += 8) {
    int e = eids[idx];
    m = fmaxf(m, score[(size_t)e * NH + h]);
  }
  #pragma unroll
  for (int off = 8; off < 64; off <<= 1) m = fmaxf(m, __shfl_xor(m, off));
  float z = 0.f;
  for (int idx = start + jj; idx < end; idx += 8) {
    int e = eids[idx];
    z += expf(score[(size_t)e * NH + h] - m);
  }
  #pragma unroll
  for (int off = 8; off < 64; off <<= 1) z += __shfl_xor(z, off);

  // redistribute to dim layout: lane owns dims {2*lane, 2*lane+1}, head = lane>>3
  int myh = lane >> 3;
  float md = __shfl(m, myh);
  float zd = __shfl(z, myh);
  float rz = (zd > 0.f) ? 1.f / zd : 0.f;

  // pass 2: weighted sum of v'
  float a0 = 0.f, a1 = 0.f;
  for (int idx = start; idx < end; idx++) {
    int e = eids[idx];
    float w = expf(score[(size_t)e * NH + myh] - md) * rz;
    u32 v2 = ((const u32*)(v_e + (size_t)e * HD))[lane];
    float v0 = __uint_as_float((v2 & 0xffffu) << 16);
    float v1 = __uint_as_float((v2 >> 16) << 16);
    a0 = fmaf(w, v0, a0);
    a1 = fmaf(w, v1, a1);
  }

  // exact GELU
  a0 = 0.5f * a0 * (1.f + erff(a0 * 0.7071067811865475f));
  a1 = 0.5f * a1 * (1.f + erff(a1 * 0.7071067811865475f));

  __shared__ __align__(16) float g[HD];
  g[2 * lane]     = a0;
  g[2 * lane + 1] = a1;
  __syncthreads();   // block == 1 wave

  int t = ntype[n];
  const float* Wt = Wa_l + (size_t)t * HD * HD;
  float o0 = ba_l[t * HD + 2 * lane];
  float o1 = ba_l[t * HD + 2 * lane + 1];
  #pragma unroll 4
  for (int k = 0; k < HD; k++) {
    float xv = g[k];
    float2 w = ((const float2*)(Wt + (size_t)k * HD))[lane];
    o0 = fmaf(xv, w.x, o0);
    o1 = fmaf(xv, w.y, o1);
  }
  float alpha = 1.f / (1.f + expf(-skip_l[t]));
  float2 xo = ((const float2*)(x + (size_t)n * HD))[lane];
  float2 xn;
  xn.x = o0 * alpha + xo.x * (1.f - alpha);
  xn.y = o1 * alpha + xo.y * (1.f - alpha);
  ((float2*)(x + (size_t)n * HD))[lane] = xn;
}

}  // namespace

extern "C" void kernel_launch(void* const* d_in, const int* in_sizes, int n_in,
                              void* d_out, int out_size, void* d_ws, size_t ws_size,
                              hipStream_t stream) {
  const float* node_feature = (const float*)d_in[0];
  const int*   node_type    = (const int*)d_in[1];
  const int*   edge_time    = (const int*)d_in[2];
  const int*   edge_type    = (const int*)d_in[3];
  const int*   edge_index   = (const int*)d_in[4];
  const float* adapt_W      = (const float*)d_in[5];
  const float* adapt_b      = (const float*)d_in[6];
  const float* Wk           = (const float*)d_in[7];
  const float* bk           = (const float*)d_in[8];
  const float* Wq           = (const float*)d_in[9];
  const float* bq           = (const float*)d_in[10];
  const float* Wv           = (const float*)d_in[11];
  const float* bv           = (const float*)d_in[12];
  const float* Wa           = (const float*)d_in[13];
  const float* ba           = (const float*)d_in[14];
  const float* rel_pri      = (const float*)d_in[15];
  const float* rel_att      = (const float*)d_in[16];
  const float* rel_msg      = (const float*)d_in[17];
  const float* skip         = (const float*)d_in[18];
  const float* rte_emb      = (const float*)d_in[19];
  const float* rte_W        = (const float*)d_in[20];
  const float* rte_b        = (const float*)d_in[21];

  const int N = in_sizes[1];
  const int E = in_sizes[2];
  const int* src  = edge_index;       // row 0
  const int* dstp = edge_index + E;   // row 1

  float* x = (float*)d_out;           // x lives in d_out; k_aggr updates in place

  // ---- workspace carve (256B aligned) ----
  size_t off = 0;
  auto carve = [&](size_t bytes) -> void* {
    void* p = (char*)d_ws + off;
    off += (bytes + 255) & ~(size_t)255;
    return p;
  };
  float* q_nodes = (float*)carve((size_t)N * HD * 4);
  float* score   = (float*)carve((size_t)E * NH * 4);
  u16*   v_e     = (u16*)  carve((size_t)E * HD * 2);
  float* rte_t   = (float*)carve((size_t)MAXT * HD * 4);
  float* Wcomb   = (float*)carve((size_t)12 * 256 * HD * 4);
  float* bcomb   = (float*)carve((size_t)12 * 256 * 4);
  int*   row_ptr = (int*)  carve((size_t)(N + 1) * 4);
  int*   cnt     = (int*)  carve((size_t)(N + 1) * 4);  // histogram, then cursor
  int*   csr_e   = (int*)  carve((size_t)E * 4);
  int*   bsums   = (int*)  carve(1024 * 4);
  int*   bcnt    = (int*)  carve(16 * 4);
  int*   bal     = (int*)  carve(16 * 4);
  int*   bcur    = (int*)  carve(16 * 4);
  const int EP = E + 12 * 64;
  int*   esorted = (int*)  carve((size_t)EP * 4);
  (void)ws_size; (void)n_in; (void)out_size;  // ~265 MB required

  const int gE  = (E + 255) / 256;
  const int gN1 = (N + 1 + 255) / 256;   // scan blocks (196 <= 256)
  const int gN  = (N + 255) / 256;
  const int gEP = (EP + 255) / 256;
  const int tiles = (EP + 63) / 64;

  // ---- CSR by destination (same for both layers) ----
  k_fill_i32<<<gN1, 256, 0, stream>>>(cnt, 0, N + 1);
  k_hist_dst<<<gE, 256, 0, stream>>>(dstp, cnt, E);
  k_scan_a<<<gN1, 256, 0, stream>>>(cnt, row_ptr, bsums, N + 1);
  k_scan_b<<<1, 256, 0, stream>>>(bsums, gN1);
  k_scan_c<<<gN1, 256, 0, stream>>>(row_ptr, bsums, N + 1);
  k_copy_i32<<<gN, 256, 0, stream>>>(cnt, row_ptr, N);
  k_scatter_dst<<<gE, 256, 0, stream>>>(dstp, cnt, csr_e, E);

  // ---- (src_type, rel_type) buckets, 64-aligned regions ----
  k_fill_i32<<<1, 256, 0, stream>>>(bcnt, 0, 16);
  k_bhist<<<gE, 256, 0, stream>>>(src, edge_type, node_type, bcnt, E);
  k_bscan<<<1, 64, 0, stream>>>(bcnt, bal, bcur);
  k_fill_i32<<<gEP, 256, 0, stream>>>(esorted, -1, EP);
  k_bscatter<<<gE, 256, 0, stream>>>(src, edge_type, node_type, bcur, esorted, E);

  // ---- adapt ----
  k_adapt<<<N, 64, 0, stream>>>(node_feature, node_type, adapt_W, adapt_b, x, N);

  // ---- layers ----
  for (int l = 0; l < 2; l++) {
    k_rte<<<MAXT, 64, 0, stream>>>(rte_emb, rte_W, rte_b, rte_t, l);
    k_wcomb<<<12 * 256, 128, 0, stream>>>(Wk, Wv, bk, bv, rel_att, rel_msg,
                                          Wcomb, bcomb, l);
    k_qnodes<<<N, 64, 0, stream>>>(x, node_type,
                                   Wq + (size_t)l * T_N * HD * HD,
                                   bq + (size_t)l * T_N * HD, q_nodes, N);
    k_edge_gemm<<<tiles, 256, 0, stream>>>(x, rte_t, Wcomb, bcomb, q_nodes,
                                           esorted, bal, src, dstp, edge_time,
                                           node_type,
                                           rel_pri + (size_t)l * T_N * R_N * T_N * NH,
                                           score, v_e);
    k_aggr<<<N, 64, 0, stream>>>(row_ptr, csr_e, score, v_e, node_type,
                                 Wa + (size_t)l * T_N * HD * HD,
                                 ba + (size_t)l * T_N * HD,
                                 skip + (size_t)l * T_N, x, N);
  }
}

// Round 6
// 2026.368 us; speedup vs baseline: 3.6026x; 2.2657x over previous
//
#include <hip/hip_runtime.h>
#include <cstdint>
#include <cstddef>

// HGT forward (2 layers) on MI355X.
// R5 change: edge K/V projection GEMM (64x256x128 per tile) moved from fp32
// VALU (19% of 157TF, latency-bound) to fp16 MFMA 16x16x32 (fp32 accum).
// A = src_vec staged in LDS as f16 with XOR swizzle (G4: 256B-stride rows are
// a bank-conflict trap); B = Wcomb precomputed f16 [c][k] (k-contiguous ->
// direct b128 fragment loads); v' stored f16 (was bf16 -> 4x less round err).

namespace {

constexpr int T_N  = 3;
constexpr int R_N  = 4;
constexpr int HD   = 128;
constexpr int IND  = 256;
constexpr int NH   = 8;
constexpr int MAXT = 240;

typedef unsigned short u16;
typedef unsigned int   u32;
typedef _Float16 f16;
typedef __attribute__((ext_vector_type(8))) _Float16 f16x8;
typedef __attribute__((ext_vector_type(4))) float    f32x4;

// ----------------------------- utility kernels -----------------------------
__global__ void k_fill_i32(int* __restrict__ p, int v, int n) {
  int i = blockIdx.x * 256 + threadIdx.x;
  if (i < n) p[i] = v;
}
__global__ void k_copy_i32(int* __restrict__ d, const int* __restrict__ s, int n) {
  int i = blockIdx.x * 256 + threadIdx.x;
  if (i < n) d[i] = s[i];
}
__global__ void k_hist_dst(const int* __restrict__ dst, int* __restrict__ cnt, int E) {
  int i = blockIdx.x * 256 + threadIdx.x;
  if (i < E) atomicAdd(&cnt[dst[i]], 1);
}
__global__ void k_scan_a(const int* __restrict__ in, int* __restrict__ out,
                         int* __restrict__ bsums, int n) {
  __shared__ int s[256];
  int gid = blockIdx.x * 256 + threadIdx.x;
  int v = (gid < n) ? in[gid] : 0;
  s[threadIdx.x] = v;
  __syncthreads();
  for (int off = 1; off < 256; off <<= 1) {
    int t = (threadIdx.x >= off) ? s[threadIdx.x - off] : 0;
    __syncthreads();
    s[threadIdx.x] += t;
    __syncthreads();
  }
  if (gid < n) out[gid] = s[threadIdx.x] - v;
  if (threadIdx.x == 255) bsums[blockIdx.x] = s[255];
}
__global__ void k_scan_b(int* __restrict__ bsums, int nb) {
  __shared__ int s[256];
  int v = (threadIdx.x < nb) ? bsums[threadIdx.x] : 0;
  s[threadIdx.x] = v;
  __syncthreads();
  for (int off = 1; off < 256; off <<= 1) {
    int t = (threadIdx.x >= off) ? s[threadIdx.x - off] : 0;
    __syncthreads();
    s[threadIdx.x] += t;
    __syncthreads();
  }
  if (threadIdx.x < nb) bsums[threadIdx.x] = s[threadIdx.x] - v;
}
__global__ void k_scan_c(int* __restrict__ out, const int* __restrict__ bsums, int n) {
  int gid = blockIdx.x * 256 + threadIdx.x;
  if (gid < n) out[gid] += bsums[blockIdx.x];
}
__global__ void k_scatter_dst(const int* __restrict__ dst, int* __restrict__ cur,
                              int* __restrict__ eids, int E) {
  int i = blockIdx.x * 256 + threadIdx.x;
  if (i < E) {
    int pos = atomicAdd(&cur[dst[i]], 1);
    eids[pos] = i;
  }
}
__global__ void k_bhist(const int* __restrict__ src, const int* __restrict__ etype,
                        const int* __restrict__ ntype, int* __restrict__ bcnt, int E) {
  __shared__ int loc[12];
  if (threadIdx.x < 12) loc[threadIdx.x] = 0;
  __syncthreads();
  int i = blockIdx.x * 256 + threadIdx.x;
  if (i < E) {
    int b = ntype[src[i]] * R_N + etype[i];
    atomicAdd(&loc[b], 1);
  }
  __syncthreads();
  if (threadIdx.x < 12) atomicAdd(&bcnt[threadIdx.x], loc[threadIdx.x]);
}
__global__ void k_bscan(const int* __restrict__ bcnt, int* __restrict__ bal,
                        int* __restrict__ bcur) {
  if (threadIdx.x == 0 && blockIdx.x == 0) {
    int run = 0;
    for (int b = 0; b < 12; b++) {
      bal[b] = run;
      bcur[b] = run;
      run += (bcnt[b] + 63) & ~63;
    }
    bal[12] = run;
  }
}
// per-block LDS histogram; one global atomic per (block,bucket)
__global__ void k_bscatter(const int* __restrict__ src, const int* __restrict__ etype,
                           const int* __restrict__ ntype, int* __restrict__ bcur,
                           int* __restrict__ esorted, int E) {
  __shared__ int loc[12];
  __shared__ int base[12];
  if (threadIdx.x < 12) loc[threadIdx.x] = 0;
  __syncthreads();
  int i = blockIdx.x * 256 + threadIdx.x;
  int b = 0, lpos = 0;
  if (i < E) {
    b = ntype[src[i]] * R_N + etype[i];
    lpos = atomicAdd(&loc[b], 1);
  }
  __syncthreads();
  if (threadIdx.x < 12) {
    int c = loc[threadIdx.x];
    base[threadIdx.x] = (c > 0) ? atomicAdd(&bcur[threadIdx.x], c) : 0;
  }
  __syncthreads();
  if (i < E) esorted[base[b] + lpos] = i;
}

// ------------------------------ math kernels -------------------------------
__global__ void k_adapt(const float* __restrict__ nf, const int* __restrict__ nt,
                        const float* __restrict__ W, const float* __restrict__ b,
                        float* __restrict__ x, int N) {
  int n = blockIdx.x;
  int lane = threadIdx.x;
  __shared__ __align__(16) float s[IND];
  ((float4*)s)[lane] = ((const float4*)(nf + (size_t)n * IND))[lane];
  __syncthreads();
  int t = nt[n];
  const float* Wt = W + (size_t)t * IND * HD;
  float o0 = b[t * HD + 2 * lane];
  float o1 = b[t * HD + 2 * lane + 1];
  #pragma unroll 4
  for (int k = 0; k < IND; k++) {
    float xv = s[k];
    float2 w = ((const float2*)(Wt + (size_t)k * HD))[lane];
    o0 = fmaf(xv, w.x, o0);
    o1 = fmaf(xv, w.y, o1);
  }
  x[(size_t)n * HD + 2 * lane]     = tanhf(o0);
  x[(size_t)n * HD + 2 * lane + 1] = tanhf(o1);
}

__global__ void k_rte(const float* __restrict__ emb, const float* __restrict__ W,
                      const float* __restrict__ bias, float* __restrict__ out, int l) {
  int t = blockIdx.x;
  int lane = threadIdx.x;
  __shared__ __align__(16) float s[2 * HD];
  ((float4*)s)[lane] = ((const float4*)(emb + (size_t)t * 2 * HD))[lane];
  __syncthreads();
  const float* Wl = W + (size_t)l * 2 * HD * HD;
  float o0 = bias[l * HD + 2 * lane];
  float o1 = bias[l * HD + 2 * lane + 1];
  #pragma unroll 4
  for (int k = 0; k < 2 * HD; k++) {
    float xv = s[k];
    float2 w = ((const float2*)(Wl + (size_t)k * HD))[lane];
    o0 = fmaf(xv, w.x, o0);
    o1 = fmaf(xv, w.y, o1);
  }
  out[t * HD + 2 * lane]     = o0;
  out[t * HD + 2 * lane + 1] = o1;
}

__global__ void k_qnodes(const float* __restrict__ x, const int* __restrict__ nt,
                         const float* __restrict__ Wq_l, const float* __restrict__ bq_l,
                         float* __restrict__ q, int N) {
  int n = blockIdx.x;
  int lane = threadIdx.x;
  __shared__ __align__(16) float s[HD];
  ((float2*)s)[lane] = ((const float2*)(x + (size_t)n * HD))[lane];
  __syncthreads();
  int t = nt[n];
  const float* Wt = Wq_l + (size_t)t * HD * HD;
  float o0 = bq_l[t * HD + 2 * lane];
  float o1 = bq_l[t * HD + 2 * lane + 1];
  #pragma unroll 4
  for (int k = 0; k < HD; k++) {
    float xv = s[k];
    float2 w = ((const float2*)(Wt + (size_t)k * HD))[lane];
    o0 = fmaf(xv, w.x, o0);
    o1 = fmaf(xv, w.y, o1);
  }
  q[(size_t)n * HD + 2 * lane]     = o0;
  q[(size_t)n * HD + 2 * lane + 1] = o1;
}

// Combined per-(type,rel) matrices, f16, stored [b][c][k] (k contiguous):
//   c<128: Wk x rel_att ; c>=128: Wv x rel_msg. bcomb fp32.
__global__ void k_wcomb(const float* __restrict__ Wk, const float* __restrict__ Wv,
                        const float* __restrict__ bk, const float* __restrict__ bv,
                        const float* __restrict__ Ratt, const float* __restrict__ Rmsg,
                        u16* __restrict__ Wcomb, float* __restrict__ bcomb, int l) {
  int bc = blockIdx.x;          // 12*256 blocks
  int b  = bc >> 8;
  int c  = bc & 255;
  int st = b >> 2, rt = b & 3;
  int k  = threadIdx.x;         // 128 threads
  bool isv = (c >= HD);
  int c0 = isv ? c - HD : c;
  int h  = c0 >> 4, cc = c0 & 15;
  const float* W = (isv ? Wv : Wk) + (((size_t)(l * T_N + st) * HD) + k) * HD + h * 16;
  const float* A = (isv ? Rmsg : Ratt) + (((size_t)(l * R_N + rt) * NH + h) * 16) * 16 + cc;
  float s = 0.f;
  #pragma unroll
  for (int d = 0; d < 16; d++) s = fmaf(W[d], A[d * 16], s);
  Wcomb[((size_t)b * 256 + c) * HD + k] = __builtin_bit_cast(u16, (f16)s);
  if (k == 0) {
    const float* bb = (isv ? bv : bk) + (size_t)(l * T_N + st) * HD + h * 16;
    float sb = 0.f;
    #pragma unroll
    for (int d = 0; d < 16; d++) sb = fmaf(bb[d], A[d * 16], sb);
    bcomb[b * 256 + c] = sb;
  }
}

// MFMA edge kernel. Per 64-edge tile of one (st,rt) bucket:
//   A[64][128] = f16(x[src]+rte) in swizzled LDS; B = Wcomb f16 [256][128];
//   D = A*B^T + bias via mfma_f32_16x16x32_f16 (wave w owns cols w*64..+64);
//   cols<128 -> k' (scores), cols>=128 -> v' (f16 global).
// Frag layouts (m89/m92/m97-verified family): A lane: row=l&15, k=8*(l>>4)+j
// (contiguous 8 -> one b128); B lane: col=l&15, same k. D: col=l&15,
// row=(l>>4)*4+reg. LDS swizzle: byte ^= (row&7)<<4 (G4 fix for 256B rows).
__global__ __launch_bounds__(256) void k_edge_gemm(
    const float* __restrict__ x, const float* __restrict__ rte_t,
    const u16* __restrict__ Wcomb, const float* __restrict__ bcomb,
    const float* __restrict__ q_nodes, const int* __restrict__ esorted,
    const int* __restrict__ bal, const int* __restrict__ src,
    const int* __restrict__ dst, const int* __restrict__ etime,
    const int* __restrict__ ntype, const float* __restrict__ pri_l,
    float* __restrict__ score, u16* __restrict__ v_e) {
  int tile0 = blockIdx.x * 64;
  if (tile0 >= bal[12]) return;
  int b = 0;
  #pragma unroll
  for (int i = 1; i < 12; i++) b += (tile0 >= bal[i]);
  int st = b >> 2, rt = b & 3;

  __shared__ __align__(16) u16 albuf[64 * HD];   // 16 KB f16, swizzled rows
  __shared__ int s_eid[64];
  __shared__ int s_dst[64];
  int tid = threadIdx.x;
  int lane = tid & 63, w = tid >> 6;
  int l15 = lane & 15, l4 = lane >> 4;

  if (tid < 64) {
    int e = esorted[tile0 + tid];
    s_eid[tid] = e;
    s_dst[tid] = (e >= 0) ? dst[e] : 0;
  }
  __syncthreads();

  { // stage src_vec -> f16 LDS: thread (row=tid>>2, quarter=tid&3), 32 vals
    int r = tid >> 2, qq = tid & 3;
    int e = s_eid[r];
    char* rowp = (char*)albuf + r * 256;
    int sw = (r & 7) << 4;
    if (e >= 0) {
      const float4* xs = (const float4*)(x + (size_t)src[e] * HD + qq * 32);
      const float4* rp = (const float4*)(rte_t + (size_t)etime[e] * HD + qq * 32);
      #pragma unroll
      for (int i = 0; i < 4; i++) {
        float4 a = xs[2 * i],     c = rp[2 * i];
        float4 a2 = xs[2 * i + 1], c2 = rp[2 * i + 1];
        f16x8 hv;
        hv[0] = (f16)(a.x + c.x);   hv[1] = (f16)(a.y + c.y);
        hv[2] = (f16)(a.z + c.z);   hv[3] = (f16)(a.w + c.w);
        hv[4] = (f16)(a2.x + c2.x); hv[5] = (f16)(a2.y + c2.y);
        hv[6] = (f16)(a2.z + c2.z); hv[7] = (f16)(a2.w + c2.w);
        *(f16x8*)(rowp + ((qq * 64 + i * 16) ^ sw)) = hv;
      }
    } else {
      f16x8 z;
      #pragma unroll
      for (int j = 0; j < 8; j++) z[j] = (f16)0.f;
      #pragma unroll
      for (int i = 0; i < 4; i++)
        *(f16x8*)(rowp + ((qq * 64 + i * 16) ^ sw)) = z;
    }
  }
  __syncthreads();

  // accumulators: 4 m-tiles x 4 n-tiles (wave w -> cols w*64..w*64+64)
  f32x4 acc[4][4];
  #pragma unroll
  for (int ni = 0; ni < 4; ni++) {
    float bc = bcomb[b * 256 + w * 64 + ni * 16 + l15];
    #pragma unroll
    for (int mi = 0; mi < 4; mi++) {
      acc[mi][ni][0] = bc; acc[mi][ni][1] = bc;
      acc[mi][ni][2] = bc; acc[mi][ni][3] = bc;
    }
  }
  const u16* Wb = Wcomb + (size_t)b * 256 * HD;
  #pragma unroll
  for (int ks = 0; ks < 4; ks++) {
    int k0 = ks * 32 + 8 * l4;          // this lane-group's k base
    f16x8 bf[4], af[4];
    #pragma unroll
    for (int ni = 0; ni < 4; ni++)
      bf[ni] = *(const f16x8*)(Wb + (size_t)(w * 64 + ni * 16 + l15) * HD + k0);
    #pragma unroll
    for (int mi = 0; mi < 4; mi++) {
      int row = mi * 16 + l15;
      af[mi] = *(const f16x8*)((const char*)albuf + row * 256 +
                               ((2 * k0) ^ ((row & 7) << 4)));
    }
    #pragma unroll
    for (int mi = 0; mi < 4; mi++)
      #pragma unroll
      for (int ni = 0; ni < 4; ni++)
        acc[mi][ni] = __builtin_amdgcn_mfma_f32_16x16x32_f16(af[mi], bf[ni],
                                                             acc[mi][ni], 0, 0, 0);
  }
  __syncthreads();   // all waves done reading albuf (A)

  if (w < 2) {       // k' (cols w*64..+64) -> albuf f16, same swizzle
    #pragma unroll
    for (int mi = 0; mi < 4; mi++)
      #pragma unroll
      for (int r = 0; r < 4; r++) {
        int row = mi * 16 + l4 * 4 + r;
        char* rowp = (char*)albuf + row * 256;
        int sw = (row & 7) << 4;
        #pragma unroll
        for (int ni = 0; ni < 4; ni++) {
          int c = w * 64 + ni * 16 + l15;
          *(u16*)(rowp + ((2 * c) ^ sw)) =
              __builtin_bit_cast(u16, (f16)acc[mi][ni][r]);
        }
      }
  } else {           // v' (cols 128..256) -> global f16
    int wv = w - 2;
    #pragma unroll
    for (int mi = 0; mi < 4; mi++)
      #pragma unroll
      for (int r = 0; r < 4; r++) {
        int e = s_eid[mi * 16 + l4 * 4 + r];
        if (e >= 0) {
          u16* vp = v_e + (size_t)e * HD + wv * 64 + l15;
          #pragma unroll
          for (int ni = 0; ni < 4; ni++)
            vp[ni * 16] = __builtin_bit_cast(u16, (f16)acc[mi][ni][r]);
        }
      }
  }
  __syncthreads();

  // scores: 512 (edge, head) tasks over 256 threads
  #pragma unroll
  for (int s = 0; s < 2; s++) {
    int p = tid + 256 * s;
    int e = p >> 3, h = p & 7;
    int eid = s_eid[e];
    if (eid >= 0) {
      int d = s_dst[e];
      int tt = ntype[d];
      const char* rowp = (const char*)albuf + e * 256;
      int sw = (e & 7) << 4;
      f16x8 kh0 = *(const f16x8*)(rowp + ((h * 32) ^ sw));
      f16x8 kh1 = *(const f16x8*)(rowp + ((h * 32 + 16) ^ sw));
      const float4* qp = (const float4*)(q_nodes + (size_t)d * HD + h * 16);
      float4 q0 = qp[0], q1 = qp[1], q2 = qp[2], q3 = qp[3];
      float sc = 0.f;
      sc += q0.x * (float)kh0[0] + q0.y * (float)kh0[1]
          + q0.z * (float)kh0[2] + q0.w * (float)kh0[3];
      sc += q1.x * (float)kh0[4] + q1.y * (float)kh0[5]
          + q1.z * (float)kh0[6] + q1.w * (float)kh0[7];
      sc += q2.x * (float)kh1[0] + q2.y * (float)kh1[1]
          + q2.z * (float)kh1[2] + q2.w * (float)kh1[3];
      sc += q3.x * (float)kh1[4] + q3.y * (float)kh1[5]
          + q3.z * (float)kh1[6] + q3.w * (float)kh1[7];
      float pri = pri_l[((tt * R_N + rt) * T_N + st) * NH + h];
      score[(size_t)eid * NH + h] = sc * pri * 0.25f;
    }
  }
}

// Per-node (1 wave): segment softmax, weighted v-sum (f16), exact GELU,
// per-type output linear, sigmoid-skip blend IN PLACE in x.
__global__ void k_aggr(const int* __restrict__ row_ptr, const int* __restrict__ eids,
                       const float* __restrict__ score, const u16* __restrict__ v_e,
                       const int* __restrict__ ntype, const float* __restrict__ Wa_l,
                       const float* __restrict__ ba_l, const float* __restrict__ skip_l,
                       float* __restrict__ x, int N) {
  int n = blockIdx.x;
  int lane = threadIdx.x;
  int start = row_ptr[n], end = row_ptr[n + 1];

  int h = lane & 7, jj = lane >> 3;
  float m = -3.0e38f;
  for (int idx = start + jj; idx < end; idx += 8) {
    int e = eids[idx];
    m = fmaxf(m, score[(size_t)e * NH + h]);
  }
  #pragma unroll
  for (int off = 8; off < 64; off <<= 1) m = fmaxf(m, __shfl_xor(m, off));
  float z = 0.f;
  for (int idx = start + jj; idx < end; idx += 8) {
    int e = eids[idx];
    z += expf(score[(size_t)e * NH + h] - m);
  }
  #pragma unroll
  for (int off = 8; off < 64; off <<= 1) z += __shfl_xor(z, off);

  int myh = lane >> 3;
  float md = __shfl(m, myh);
  float zd = __shfl(z, myh);
  float rz = (zd > 0.f) ? 1.f / zd : 0.f;

  float a0 = 0.f, a1 = 0.f;
  for (int idx = start; idx < end; idx++) {
    int e = eids[idx];
    float wgt = expf(score[(size_t)e * NH + myh] - md) * rz;
    u32 v2 = ((const u32*)(v_e + (size_t)e * HD))[lane];
    float v0 = (float)__builtin_bit_cast(f16, (u16)(v2 & 0xffffu));
    float v1 = (float)__builtin_bit_cast(f16, (u16)(v2 >> 16));
    a0 = fmaf(wgt, v0, a0);
    a1 = fmaf(wgt, v1, a1);
  }

  a0 = 0.5f * a0 * (1.f + erff(a0 * 0.7071067811865475f));
  a1 = 0.5f * a1 * (1.f + erff(a1 * 0.7071067811865475f));

  __shared__ __align__(16) float g[HD];
  g[2 * lane]     = a0;
  g[2 * lane + 1] = a1;
  __syncthreads();

  int t = ntype[n];
  const float* Wt = Wa_l + (size_t)t * HD * HD;
  float o0 = ba_l[t * HD + 2 * lane];
  float o1 = ba_l[t * HD + 2 * lane + 1];
  #pragma unroll 4
  for (int k = 0; k < HD; k++) {
    float xv = g[k];
    float2 w = ((const float2*)(Wt + (size_t)k * HD))[lane];
    o0 = fmaf(xv, w.x, o0);
    o1 = fmaf(xv, w.y, o1);
  }
  float alpha = 1.f / (1.f + expf(-skip_l[t]));
  float2 xo = ((const float2*)(x + (size_t)n * HD))[lane];
  float2 xn;
  xn.x = o0 * alpha + xo.x * (1.f - alpha);
  xn.y = o1 * alpha + xo.y * (1.f - alpha);
  ((float2*)(x + (size_t)n * HD))[lane] = xn;
}

}  // namespace

extern "C" void kernel_launch(void* const* d_in, const int* in_sizes, int n_in,
                              void* d_out, int out_size, void* d_ws, size_t ws_size,
                              hipStream_t stream) {
  const float* node_feature = (const float*)d_in[0];
  const int*   node_type    = (const int*)d_in[1];
  const int*   edge_time    = (const int*)d_in[2];
  const int*   edge_type    = (const int*)d_in[3];
  const int*   edge_index   = (const int*)d_in[4];
  const float* adapt_W      = (const float*)d_in[5];
  const float* adapt_b      = (const float*)d_in[6];
  const float* Wk           = (const float*)d_in[7];
  const float* bk           = (const float*)d_in[8];
  const float* Wq           = (const float*)d_in[9];
  const float* bq           = (const float*)d_in[10];
  const float* Wv           = (const float*)d_in[11];
  const float* bv           = (const float*)d_in[12];
  const float* Wa           = (const float*)d_in[13];
  const float* ba           = (const float*)d_in[14];
  const float* rel_pri      = (const float*)d_in[15];
  const float* rel_att      = (const float*)d_in[16];
  const float* rel_msg      = (const float*)d_in[17];
  const float* skip         = (const float*)d_in[18];
  const float* rte_emb      = (const float*)d_in[19];
  const float* rte_W        = (const float*)d_in[20];
  const float* rte_b        = (const float*)d_in[21];

  const int N = in_sizes[1];
  const int E = in_sizes[2];
  const int* src  = edge_index;
  const int* dstp = edge_index + E;

  float* x = (float*)d_out;

  size_t off = 0;
  auto carve = [&](size_t bytes) -> void* {
    void* p = (char*)d_ws + off;
    off += (bytes + 255) & ~(size_t)255;
    return p;
  };
  float* q_nodes = (float*)carve((size_t)N * HD * 4);
  float* score   = (float*)carve((size_t)E * NH * 4);
  u16*   v_e     = (u16*)  carve((size_t)E * HD * 2);
  float* rte_t   = (float*)carve((size_t)MAXT * HD * 4);
  u16*   Wcomb   = (u16*)  carve((size_t)12 * 256 * HD * 2);
  float* bcomb   = (float*)carve((size_t)12 * 256 * 4);
  int*   row_ptr = (int*)  carve((size_t)(N + 1) * 4);
  int*   cnt     = (int*)  carve((size_t)(N + 1) * 4);
  int*   csr_e   = (int*)  carve((size_t)E * 4);
  int*   bsums   = (int*)  carve(1024 * 4);
  int*   bcnt    = (int*)  carve(16 * 4);
  int*   bal     = (int*)  carve(16 * 4);
  int*   bcur    = (int*)  carve(16 * 4);
  const int EP = E + 12 * 64;
  int*   esorted = (int*)  carve((size_t)EP * 4);
  (void)ws_size; (void)n_in; (void)out_size;

  const int gE  = (E + 255) / 256;
  const int gN1 = (N + 1 + 255) / 256;
  const int gN  = (N + 255) / 256;
  const int gEP = (EP + 255) / 256;
  const int tiles = (EP + 63) / 64;

  // CSR by destination (shared by both layers)
  k_fill_i32<<<gN1, 256, 0, stream>>>(cnt, 0, N + 1);
  k_hist_dst<<<gE, 256, 0, stream>>>(dstp, cnt, E);
  k_scan_a<<<gN1, 256, 0, stream>>>(cnt, row_ptr, bsums, N + 1);
  k_scan_b<<<1, 256, 0, stream>>>(bsums, gN1);
  k_scan_c<<<gN1, 256, 0, stream>>>(row_ptr, bsums, N + 1);
  k_copy_i32<<<gN, 256, 0, stream>>>(cnt, row_ptr, N);
  k_scatter_dst<<<gE, 256, 0, stream>>>(dstp, cnt, csr_e, E);

  // (src_type, rel_type) buckets, 64-aligned
  k_fill_i32<<<1, 256, 0, stream>>>(bcnt, 0, 16);
  k_bhist<<<gE, 256, 0, stream>>>(src, edge_type, node_type, bcnt, E);
  k_bscan<<<1, 64, 0, stream>>>(bcnt, bal, bcur);
  k_fill_i32<<<gEP, 256, 0, stream>>>(esorted, -1, EP);
  k_bscatter<<<gE, 256, 0, stream>>>(src, edge_type, node_type, bcur, esorted, E);

  k_adapt<<<N, 64, 0, stream>>>(node_feature, node_type, adapt_W, adapt_b, x, N);

  for (int l = 0; l < 2; l++) {
    k_rte<<<MAXT, 64, 0, stream>>>(rte_emb, rte_W, rte_b, rte_t, l);
    k_wcomb<<<12 * 256, 128, 0, stream>>>(Wk, Wv, bk, bv, rel_att, rel_msg,
                                          Wcomb, bcomb, l);
    k_qnodes<<<N, 64, 0, stream>>>(x, node_type,
                                   Wq + (size_t)l * T_N * HD * HD,
                                   bq + (size_t)l * T_N * HD, q_nodes, N);
    k_edge_gemm<<<tiles, 256, 0, stream>>>(x, rte_t, Wcomb, bcomb, q_nodes,
                                           esorted, bal, src, dstp, edge_time,
                                           node_type,
                                           rel_pri + (size_t)l * T_N * R_N * T_N * NH,
                                           score, v_e);
    k_aggr<<<N, 64, 0, stream>>>(row_ptr, csr_e, score, v_e, node_type,
                                 Wa + (size_t)l * T_N * HD * HD,
                                 ba + (size_t)l * T_N * HD,
                                 skip + (size_t)l * T_N, x, N);
  }
}

// Round 7
// 1151.863 us; speedup vs baseline: 6.3376x; 1.7592x over previous
//
#include <hip/hip_runtime.h>
#include <cstdint>
#include <cstddef>

// HGT forward (2 layers) on MI355X.
// R6: all per-type NODE linears (adapt K=256, q K=128, out-linear K=128) moved
// to a single MFMA tile engine over type-sorted 64-node buckets. Fixes the
// zero-weight-reuse pathology (k_adapt: 50000 waves x 128KB = 6.5 TB L2
// traffic, 397us at 11% VALUBusy). k_aggr now only does softmax+v-sum+gelu
// and writes g into the dead q_nodes buffer; the Wa linear + skip blend is a
// ngemm pass. Edge K/V GEMM (MFMA, R5) unchanged.

namespace {

constexpr int T_N  = 3;
constexpr int R_N  = 4;
constexpr int HD   = 128;
constexpr int IND  = 256;
constexpr int NH   = 8;
constexpr int MAXT = 240;

typedef unsigned short u16;
typedef unsigned int   u32;
typedef _Float16 f16;
typedef __attribute__((ext_vector_type(8))) _Float16 f16x8;
typedef __attribute__((ext_vector_type(4))) float    f32x4;

// ----------------------------- utility kernels -----------------------------
__global__ void k_fill_i32(int* __restrict__ p, int v, int n) {
  int i = blockIdx.x * 256 + threadIdx.x;
  if (i < n) p[i] = v;
}
__global__ void k_copy_i32(int* __restrict__ d, const int* __restrict__ s, int n) {
  int i = blockIdx.x * 256 + threadIdx.x;
  if (i < n) d[i] = s[i];
}
__global__ void k_hist_dst(const int* __restrict__ dst, int* __restrict__ cnt, int E) {
  int i = blockIdx.x * 256 + threadIdx.x;
  if (i < E) atomicAdd(&cnt[dst[i]], 1);
}
__global__ void k_scan_a(const int* __restrict__ in, int* __restrict__ out,
                         int* __restrict__ bsums, int n) {
  __shared__ int s[256];
  int gid = blockIdx.x * 256 + threadIdx.x;
  int v = (gid < n) ? in[gid] : 0;
  s[threadIdx.x] = v;
  __syncthreads();
  for (int off = 1; off < 256; off <<= 1) {
    int t = (threadIdx.x >= off) ? s[threadIdx.x - off] : 0;
    __syncthreads();
    s[threadIdx.x] += t;
    __syncthreads();
  }
  if (gid < n) out[gid] = s[threadIdx.x] - v;
  if (threadIdx.x == 255) bsums[blockIdx.x] = s[255];
}
__global__ void k_scan_b(int* __restrict__ bsums, int nb) {
  __shared__ int s[256];
  int v = (threadIdx.x < nb) ? bsums[threadIdx.x] : 0;
  s[threadIdx.x] = v;
  __syncthreads();
  for (int off = 1; off < 256; off <<= 1) {
    int t = (threadIdx.x >= off) ? s[threadIdx.x - off] : 0;
    __syncthreads();
    s[threadIdx.x] += t;
    __syncthreads();
  }
  if (threadIdx.x < nb) bsums[threadIdx.x] = s[threadIdx.x] - v;
}
__global__ void k_scan_c(int* __restrict__ out, const int* __restrict__ bsums, int n) {
  int gid = blockIdx.x * 256 + threadIdx.x;
  if (gid < n) out[gid] += bsums[blockIdx.x];
}
__global__ void k_scatter_dst(const int* __restrict__ dst, int* __restrict__ cur,
                              int* __restrict__ eids, int E) {
  int i = blockIdx.x * 256 + threadIdx.x;
  if (i < E) {
    int pos = atomicAdd(&cur[dst[i]], 1);
    eids[pos] = i;
  }
}
__global__ void k_bhist(const int* __restrict__ src, const int* __restrict__ etype,
                        const int* __restrict__ ntype, int* __restrict__ bcnt, int E) {
  __shared__ int loc[12];
  if (threadIdx.x < 12) loc[threadIdx.x] = 0;
  __syncthreads();
  int i = blockIdx.x * 256 + threadIdx.x;
  if (i < E) {
    int b = ntype[src[i]] * R_N + etype[i];
    atomicAdd(&loc[b], 1);
  }
  __syncthreads();
  if (threadIdx.x < 12) atomicAdd(&bcnt[threadIdx.x], loc[threadIdx.x]);
}
__global__ void k_bscan(const int* __restrict__ bcnt, int* __restrict__ bal,
                        int* __restrict__ bcur) {
  if (threadIdx.x == 0 && blockIdx.x == 0) {
    int run = 0;
    for (int b = 0; b < 12; b++) {
      bal[b] = run;
      bcur[b] = run;
      run += (bcnt[b] + 63) & ~63;
    }
    bal[12] = run;
  }
}
__global__ void k_bscatter(const int* __restrict__ src, const int* __restrict__ etype,
                           const int* __restrict__ ntype, int* __restrict__ bcur,
                           int* __restrict__ esorted, int E) {
  __shared__ int loc[12];
  __shared__ int base[12];
  if (threadIdx.x < 12) loc[threadIdx.x] = 0;
  __syncthreads();
  int i = blockIdx.x * 256 + threadIdx.x;
  int b = 0, lpos = 0;
  if (i < E) {
    b = ntype[src[i]] * R_N + etype[i];
    lpos = atomicAdd(&loc[b], 1);
  }
  __syncthreads();
  if (threadIdx.x < 12) {
    int c = loc[threadIdx.x];
    base[threadIdx.x] = (c > 0) ? atomicAdd(&bcur[threadIdx.x], c) : 0;
  }
  __syncthreads();
  if (i < E) esorted[base[b] + lpos] = i;
}
// node-type buckets (3), 64-aligned
__global__ void k_nhist(const int* __restrict__ ntype, int* __restrict__ ncnt, int N) {
  __shared__ int loc[3];
  if (threadIdx.x < 3) loc[threadIdx.x] = 0;
  __syncthreads();
  int i = blockIdx.x * 256 + threadIdx.x;
  if (i < N) atomicAdd(&loc[ntype[i]], 1);
  __syncthreads();
  if (threadIdx.x < 3) atomicAdd(&ncnt[threadIdx.x], loc[threadIdx.x]);
}
__global__ void k_nscan(const int* __restrict__ ncnt, int* __restrict__ nal,
                        int* __restrict__ ncur) {
  if (threadIdx.x == 0 && blockIdx.x == 0) {
    int run = 0;
    for (int t = 0; t < 3; t++) {
      nal[t] = run;
      ncur[t] = run;
      run += (ncnt[t] + 63) & ~63;
    }
    nal[3] = run;
  }
}
__global__ void k_nscatter(const int* __restrict__ ntype, int* __restrict__ ncur,
                           int* __restrict__ nsorted, int N) {
  __shared__ int loc[3];
  __shared__ int base[3];
  if (threadIdx.x < 3) loc[threadIdx.x] = 0;
  __syncthreads();
  int i = blockIdx.x * 256 + threadIdx.x;
  int t = 0, lpos = 0;
  if (i < N) {
    t = ntype[i];
    lpos = atomicAdd(&loc[t], 1);
  }
  __syncthreads();
  if (threadIdx.x < 3) {
    int c = loc[threadIdx.x];
    base[threadIdx.x] = (c > 0) ? atomicAdd(&ncur[threadIdx.x], c) : 0;
  }
  __syncthreads();
  if (i < N) nsorted[base[t] + lpos] = i;
}

// transpose+f16: src [T][Kd][Cd] fp32 -> dst [T][Cd][Kd] f16 (k contiguous)
__global__ void k_transp(const float* __restrict__ src, u16* __restrict__ dst,
                         int Kd, int Cd) {
  int c = blockIdx.x;
  int t = blockIdx.y;
  for (int k = threadIdx.x; k < Kd; k += blockDim.x)
    dst[((size_t)t * Cd + c) * Kd + k] =
        __builtin_bit_cast(u16, (f16)src[((size_t)t * Kd + k) * Cd + c]);
}

// ------------------------------ math kernels -------------------------------
__global__ void k_rte(const float* __restrict__ emb, const float* __restrict__ W,
                      const float* __restrict__ bias, float* __restrict__ out, int l) {
  int t = blockIdx.x;
  int lane = threadIdx.x;
  __shared__ __align__(16) float s[2 * HD];
  ((float4*)s)[lane] = ((const float4*)(emb + (size_t)t * 2 * HD))[lane];
  __syncthreads();
  const float* Wl = W + (size_t)l * 2 * HD * HD;
  float o0 = bias[l * HD + 2 * lane];
  float o1 = bias[l * HD + 2 * lane + 1];
  #pragma unroll 4
  for (int k = 0; k < 2 * HD; k++) {
    float xv = s[k];
    float2 w = ((const float2*)(Wl + (size_t)k * HD))[lane];
    o0 = fmaf(xv, w.x, o0);
    o1 = fmaf(xv, w.y, o1);
  }
  out[t * HD + 2 * lane]     = o0;
  out[t * HD + 2 * lane + 1] = o1;
}

// Combined per-(type,rel) matrices, f16, stored [b][c][k] (k contiguous)
__global__ void k_wcomb(const float* __restrict__ Wk, const float* __restrict__ Wv,
                        const float* __restrict__ bk, const float* __restrict__ bv,
                        const float* __restrict__ Ratt, const float* __restrict__ Rmsg,
                        u16* __restrict__ Wcomb, float* __restrict__ bcomb, int l) {
  int bc = blockIdx.x;
  int b  = bc >> 8;
  int c  = bc & 255;
  int st = b >> 2, rt = b & 3;
  int k  = threadIdx.x;
  bool isv = (c >= HD);
  int c0 = isv ? c - HD : c;
  int h  = c0 >> 4, cc = c0 & 15;
  const float* W = (isv ? Wv : Wk) + (((size_t)(l * T_N + st) * HD) + k) * HD + h * 16;
  const float* A = (isv ? Rmsg : Ratt) + (((size_t)(l * R_N + rt) * NH + h) * 16) * 16 + cc;
  float s = 0.f;
  #pragma unroll
  for (int d = 0; d < 16; d++) s = fmaf(W[d], A[d * 16], s);
  Wcomb[((size_t)b * 256 + c) * HD + k] = __builtin_bit_cast(u16, (f16)s);
  if (k == 0) {
    const float* bb = (isv ? bv : bk) + (size_t)(l * T_N + st) * HD + h * 16;
    float sb = 0.f;
    #pragma unroll
    for (int d = 0; d < 16; d++) sb = fmaf(bb[d], A[d * 16], sb);
    bcomb[b * 256 + c] = sb;
  }
}

// Generic MFMA node linear over type-sorted buckets.
// Per 64-node tile: out[n][0..128) = act( A[n][0..K) @ WT[t]^T + bias[t] ).
// ACT: 0 = tanh (adapt), 1 = none (q), 2 = skip-blend into xio.
// 4 waves; wave w -> cols w*32..w*32+32 (2 n-tiles), 4 m-tiles; K/32 k-steps.
template<int K, int ACT>
__global__ __launch_bounds__(256) void k_ngemm(
    const float* __restrict__ Asrc,    // [N][K]
    const u16* __restrict__ WT,        // [3][128][K] f16
    const float* __restrict__ bias,    // [3][128]
    const int* __restrict__ nsorted, const int* __restrict__ nal,
    const float* __restrict__ skip_l,  // ACT==2
    float* __restrict__ out,           // [N][128]
    const float* __restrict__ xin) {   // ACT==2: old x
  int tile0 = blockIdx.x * 64;
  if (tile0 >= nal[3]) return;
  int t = 0;
  #pragma unroll
  for (int i = 1; i < 3; i++) t += (tile0 >= nal[i]);

  __shared__ __align__(16) u16 ab[64 * K];   // f16, XOR-swizzled rows (G4)
  __shared__ int s_nid[64];
  int tid = threadIdx.x;
  int lane = tid & 63, w = tid >> 6;
  int l15 = lane & 15, l4 = lane >> 4;

  if (tid < 64) s_nid[tid] = nsorted[tile0 + tid];
  __syncthreads();

  { // stage: thread (row=tid>>2, quarter=tid&3) -> K/4 floats -> f16
    int r = tid >> 2, q4 = tid & 3;
    int nid = s_nid[r];
    char* rowp = (char*)ab + r * (2 * K);
    int sw = (r & 7) << 4;
    int base = q4 * (K / 2);               // byte base within row
    if (nid >= 0) {
      const float4* ap = (const float4*)(Asrc + (size_t)nid * K + q4 * (K / 4));
      #pragma unroll
      for (int i = 0; i < K / 32; i++) {
        float4 a = ap[2 * i], a2 = ap[2 * i + 1];
        f16x8 hv;
        hv[0] = (f16)a.x;  hv[1] = (f16)a.y;  hv[2] = (f16)a.z;  hv[3] = (f16)a.w;
        hv[4] = (f16)a2.x; hv[5] = (f16)a2.y; hv[6] = (f16)a2.z; hv[7] = (f16)a2.w;
        *(f16x8*)(rowp + ((base + 16 * i) ^ sw)) = hv;
      }
    } else {
      f16x8 z;
      #pragma unroll
      for (int j = 0; j < 8; j++) z[j] = (f16)0.f;
      #pragma unroll
      for (int i = 0; i < K / 32; i++)
        *(f16x8*)(rowp + ((base + 16 * i) ^ sw)) = z;
    }
  }
  __syncthreads();

  f32x4 acc[4][2];
  #pragma unroll
  for (int ni = 0; ni < 2; ni++) {
    float bc = bias[t * HD + w * 32 + ni * 16 + l15];
    #pragma unroll
    for (int mi = 0; mi < 4; mi++) {
      acc[mi][ni][0] = bc; acc[mi][ni][1] = bc;
      acc[mi][ni][2] = bc; acc[mi][ni][3] = bc;
    }
  }
  const u16* Wt = WT + (size_t)t * HD * K;
  #pragma unroll
  for (int ks = 0; ks < K / 32; ks++) {
    int k0 = ks * 32 + 8 * l4;
    f16x8 bf[2], af[4];
    #pragma unroll
    for (int ni = 0; ni < 2; ni++)
      bf[ni] = *(const f16x8*)(Wt + (size_t)(w * 32 + ni * 16 + l15) * K + k0);
    #pragma unroll
    for (int mi = 0; mi < 4; mi++) {
      int row = mi * 16 + l15;
      af[mi] = *(const f16x8*)((const char*)ab + row * (2 * K) +
                               ((2 * k0) ^ ((row & 7) << 4)));
    }
    #pragma unroll
    for (int mi = 0; mi < 4; mi++)
      #pragma unroll
      for (int ni = 0; ni < 2; ni++)
        acc[mi][ni] = __builtin_amdgcn_mfma_f32_16x16x32_f16(af[mi], bf[ni],
                                                             acc[mi][ni], 0, 0, 0);
  }

  float alpha = 0.f;
  if (ACT == 2) alpha = 1.f / (1.f + expf(-skip_l[t]));
  #pragma unroll
  for (int mi = 0; mi < 4; mi++)
    #pragma unroll
    for (int r = 0; r < 4; r++) {
      int rowl = mi * 16 + l4 * 4 + r;
      int nid = s_nid[rowl];
      if (nid >= 0) {
        #pragma unroll
        for (int ni = 0; ni < 2; ni++) {
          int c = w * 32 + ni * 16 + l15;
          float val = acc[mi][ni][r];
          if (ACT == 0) val = tanhf(val);
          if (ACT == 2) {
            float xo = xin[(size_t)nid * HD + c];
            val = val * alpha + xo * (1.f - alpha);
          }
          out[(size_t)nid * HD + c] = val;
        }
      }
    }
}

// MFMA edge kernel (R5, unchanged). Per 64-edge tile of one (st,rt) bucket.
__global__ __launch_bounds__(256) void k_edge_gemm(
    const float* __restrict__ x, const float* __restrict__ rte_t,
    const u16* __restrict__ Wcomb, const float* __restrict__ bcomb,
    const float* __restrict__ q_nodes, const int* __restrict__ esorted,
    const int* __restrict__ bal, const int* __restrict__ src,
    const int* __restrict__ dst, const int* __restrict__ etime,
    const int* __restrict__ ntype, const float* __restrict__ pri_l,
    float* __restrict__ score, u16* __restrict__ v_e) {
  int tile0 = blockIdx.x * 64;
  if (tile0 >= bal[12]) return;
  int b = 0;
  #pragma unroll
  for (int i = 1; i < 12; i++) b += (tile0 >= bal[i]);
  int st = b >> 2, rt = b & 3;

  __shared__ __align__(16) u16 albuf[64 * HD];
  __shared__ int s_eid[64];
  __shared__ int s_dst[64];
  int tid = threadIdx.x;
  int lane = tid & 63, w = tid >> 6;
  int l15 = lane & 15, l4 = lane >> 4;

  if (tid < 64) {
    int e = esorted[tile0 + tid];
    s_eid[tid] = e;
    s_dst[tid] = (e >= 0) ? dst[e] : 0;
  }
  __syncthreads();

  {
    int r = tid >> 2, qq = tid & 3;
    int e = s_eid[r];
    char* rowp = (char*)albuf + r * 256;
    int sw = (r & 7) << 4;
    if (e >= 0) {
      const float4* xs = (const float4*)(x + (size_t)src[e] * HD + qq * 32);
      const float4* rp = (const float4*)(rte_t + (size_t)etime[e] * HD + qq * 32);
      #pragma unroll
      for (int i = 0; i < 4; i++) {
        float4 a = xs[2 * i],      c = rp[2 * i];
        float4 a2 = xs[2 * i + 1], c2 = rp[2 * i + 1];
        f16x8 hv;
        hv[0] = (f16)(a.x + c.x);   hv[1] = (f16)(a.y + c.y);
        hv[2] = (f16)(a.z + c.z);   hv[3] = (f16)(a.w + c.w);
        hv[4] = (f16)(a2.x + c2.x); hv[5] = (f16)(a2.y + c2.y);
        hv[6] = (f16)(a2.z + c2.z); hv[7] = (f16)(a2.w + c2.w);
        *(f16x8*)(rowp + ((qq * 64 + i * 16) ^ sw)) = hv;
      }
    } else {
      f16x8 z;
      #pragma unroll
      for (int j = 0; j < 8; j++) z[j] = (f16)0.f;
      #pragma unroll
      for (int i = 0; i < 4; i++)
        *(f16x8*)(rowp + ((qq * 64 + i * 16) ^ sw)) = z;
    }
  }
  __syncthreads();

  f32x4 acc[4][4];
  #pragma unroll
  for (int ni = 0; ni < 4; ni++) {
    float bc = bcomb[b * 256 + w * 64 + ni * 16 + l15];
    #pragma unroll
    for (int mi = 0; mi < 4; mi++) {
      acc[mi][ni][0] = bc; acc[mi][ni][1] = bc;
      acc[mi][ni][2] = bc; acc[mi][ni][3] = bc;
    }
  }
  const u16* Wb = Wcomb + (size_t)b * 256 * HD;
  #pragma unroll
  for (int ks = 0; ks < 4; ks++) {
    int k0 = ks * 32 + 8 * l4;
    f16x8 bf[4], af[4];
    #pragma unroll
    for (int ni = 0; ni < 4; ni++)
      bf[ni] = *(const f16x8*)(Wb + (size_t)(w * 64 + ni * 16 + l15) * HD + k0);
    #pragma unroll
    for (int mi = 0; mi < 4; mi++) {
      int row = mi * 16 + l15;
      af[mi] = *(const f16x8*)((const char*)albuf + row * 256 +
                               ((2 * k0) ^ ((row & 7) << 4)));
    }
    #pragma unroll
    for (int mi = 0; mi < 4; mi++)
      #pragma unroll
      for (int ni = 0; ni < 4; ni++)
        acc[mi][ni] = __builtin_amdgcn_mfma_f32_16x16x32_f16(af[mi], bf[ni],
                                                             acc[mi][ni], 0, 0, 0);
  }
  __syncthreads();

  if (w < 2) {
    #pragma unroll
    for (int mi = 0; mi < 4; mi++)
      #pragma unroll
      for (int r = 0; r < 4; r++) {
        int row = mi * 16 + l4 * 4 + r;
        char* rowp = (char*)albuf + row * 256;
        int sw = (row & 7) << 4;
        #pragma unroll
        for (int ni = 0; ni < 4; ni++) {
          int c = w * 64 + ni * 16 + l15;
          *(u16*)(rowp + ((2 * c) ^ sw)) =
              __builtin_bit_cast(u16, (f16)acc[mi][ni][r]);
        }
      }
  } else {
    int wv = w - 2;
    #pragma unroll
    for (int mi = 0; mi < 4; mi++)
      #pragma unroll
      for (int r = 0; r < 4; r++) {
        int e = s_eid[mi * 16 + l4 * 4 + r];
        if (e >= 0) {
          u16* vp = v_e + (size_t)e * HD + wv * 64 + l15;
          #pragma unroll
          for (int ni = 0; ni < 4; ni++)
            vp[ni * 16] = __builtin_bit_cast(u16, (f16)acc[mi][ni][r]);
        }
      }
  }
  __syncthreads();

  #pragma unroll
  for (int s = 0; s < 2; s++) {
    int p = tid + 256 * s;
    int e = p >> 3, h = p & 7;
    int eid = s_eid[e];
    if (eid >= 0) {
      int d = s_dst[e];
      int tt = ntype[d];
      const char* rowp = (const char*)albuf + e * 256;
      int sw = (e & 7) << 4;
      f16x8 kh0 = *(const f16x8*)(rowp + ((h * 32) ^ sw));
      f16x8 kh1 = *(const f16x8*)(rowp + ((h * 32 + 16) ^ sw));
      const float4* qp = (const float4*)(q_nodes + (size_t)d * HD + h * 16);
      float4 q0 = qp[0], q1 = qp[1], q2 = qp[2], q3 = qp[3];
      float sc = 0.f;
      sc += q0.x * (float)kh0[0] + q0.y * (float)kh0[1]
          + q0.z * (float)kh0[2] + q0.w * (float)kh0[3];
      sc += q1.x * (float)kh0[4] + q1.y * (float)kh0[5]
          + q1.z * (float)kh0[6] + q1.w * (float)kh0[7];
      sc += q2.x * (float)kh1[0] + q2.y * (float)kh1[1]
          + q2.z * (float)kh1[2] + q2.w * (float)kh1[3];
      sc += q3.x * (float)kh1[4] + q3.y * (float)kh1[5]
          + q3.z * (float)kh1[6] + q3.w * (float)kh1[7];
      float pri = pri_l[((tt * R_N + rt) * T_N + st) * NH + h];
      score[(size_t)eid * NH + h] = sc * pri * 0.25f;
    }
  }
}

// Per-node (1 wave): segment softmax over incoming edges, weighted v-sum,
// exact GELU -> g (the Wa linear + skip blend is a k_ngemm<128,2> pass).
__global__ void k_aggr(const int* __restrict__ row_ptr, const int* __restrict__ eids,
                       const float* __restrict__ score, const u16* __restrict__ v_e,
                       float* __restrict__ g, int N) {
  int n = blockIdx.x;
  int lane = threadIdx.x;
  int start = row_ptr[n], end = row_ptr[n + 1];

  int h = lane & 7, jj = lane >> 3;
  float m = -3.0e38f;
  for (int idx = start + jj; idx < end; idx += 8) {
    int e = eids[idx];
    m = fmaxf(m, score[(size_t)e * NH + h]);
  }
  #pragma unroll
  for (int off = 8; off < 64; off <<= 1) m = fmaxf(m, __shfl_xor(m, off));
  float z = 0.f;
  for (int idx = start + jj; idx < end; idx += 8) {
    int e = eids[idx];
    z += expf(score[(size_t)e * NH + h] - m);
  }
  #pragma unroll
  for (int off = 8; off < 64; off <<= 1) z += __shfl_xor(z, off);

  int myh = lane >> 3;
  float md = __shfl(m, myh);
  float zd = __shfl(z, myh);
  float rz = (zd > 0.f) ? 1.f / zd : 0.f;

  float a0 = 0.f, a1 = 0.f;
  for (int idx = start; idx < end; idx++) {
    int e = eids[idx];
    float wgt = expf(score[(size_t)e * NH + myh] - md) * rz;
    u32 v2 = ((const u32*)(v_e + (size_t)e * HD))[lane];
    float v0 = (float)__builtin_bit_cast(f16, (u16)(v2 & 0xffffu));
    float v1 = (float)__builtin_bit_cast(f16, (u16)(v2 >> 16));
    a0 = fmaf(wgt, v0, a0);
    a1 = fmaf(wgt, v1, a1);
  }

  a0 = 0.5f * a0 * (1.f + erff(a0 * 0.7071067811865475f));
  a1 = 0.5f * a1 * (1.f + erff(a1 * 0.7071067811865475f));
  ((float2*)(g + (size_t)n * HD))[lane] = float2{a0, a1};
}

}  // namespace

extern "C" void kernel_launch(void* const* d_in, const int* in_sizes, int n_in,
                              void* d_out, int out_size, void* d_ws, size_t ws_size,
                              hipStream_t stream) {
  const float* node_feature = (const float*)d_in[0];
  const int*   node_type    = (const int*)d_in[1];
  const int*   edge_time    = (const int*)d_in[2];
  const int*   edge_type    = (const int*)d_in[3];
  const int*   edge_index   = (const int*)d_in[4];
  const float* adapt_W      = (const float*)d_in[5];
  const float* adapt_b      = (const float*)d_in[6];
  const float* Wk           = (const float*)d_in[7];
  const float* bk           = (const float*)d_in[8];
  const float* Wq           = (const float*)d_in[9];
  const float* bq           = (const float*)d_in[10];
  const float* Wv           = (const float*)d_in[11];
  const float* bv           = (const float*)d_in[12];
  const float* Wa           = (const float*)d_in[13];
  const float* ba           = (const float*)d_in[14];
  const float* rel_pri      = (const float*)d_in[15];
  const float* rel_att      = (const float*)d_in[16];
  const float* rel_msg      = (const float*)d_in[17];
  const float* skip         = (const float*)d_in[18];
  const float* rte_emb      = (const float*)d_in[19];
  const float* rte_W        = (const float*)d_in[20];
  const float* rte_b        = (const float*)d_in[21];

  const int N = in_sizes[1];
  const int E = in_sizes[2];
  const int* src  = edge_index;
  const int* dstp = edge_index + E;

  float* x = (float*)d_out;

  size_t off = 0;
  auto carve = [&](size_t bytes) -> void* {
    void* p = (char*)d_ws + off;
    off += (bytes + 255) & ~(size_t)255;
    return p;
  };
  float* q_nodes = (float*)carve((size_t)N * HD * 4);   // doubles as g buffer
  float* score   = (float*)carve((size_t)E * NH * 4);
  u16*   v_e     = (u16*)  carve((size_t)E * HD * 2);
  float* rte_t   = (float*)carve((size_t)MAXT * HD * 4);
  u16*   Wcomb   = (u16*)  carve((size_t)12 * 256 * HD * 2);
  float* bcomb   = (float*)carve((size_t)12 * 256 * 4);
  u16*   adaptWT = (u16*)  carve((size_t)T_N * HD * IND * 2);
  u16*   WqT     = (u16*)  carve((size_t)2 * T_N * HD * HD * 2);
  u16*   WaT     = (u16*)  carve((size_t)2 * T_N * HD * HD * 2);
  int*   row_ptr = (int*)  carve((size_t)(N + 1) * 4);
  int*   cnt     = (int*)  carve((size_t)(N + 1) * 4);
  int*   csr_e   = (int*)  carve((size_t)E * 4);
  int*   bsums   = (int*)  carve(1024 * 4);
  int*   bcnt    = (int*)  carve(16 * 4);
  int*   bal     = (int*)  carve(16 * 4);
  int*   bcur    = (int*)  carve(16 * 4);
  int*   ncnt    = (int*)  carve(16 * 4);
  int*   nal     = (int*)  carve(16 * 4);
  int*   ncur    = (int*)  carve(16 * 4);
  const int EP = E + 12 * 64;
  const int NP = N + 3 * 64;
  int*   esorted = (int*)  carve((size_t)EP * 4);
  int*   nsorted = (int*)  carve((size_t)NP * 4);
  (void)ws_size; (void)n_in; (void)out_size;

  const int gE  = (E + 255) / 256;
  const int gN1 = (N + 1 + 255) / 256;
  const int gN  = (N + 255) / 256;
  const int gEP = (EP + 255) / 256;
  const int gNP = (NP + 255) / 256;
  const int etiles = (EP + 63) / 64;
  const int ntiles = (NP + 63) / 64;

  // CSR by destination
  k_fill_i32<<<gN1, 256, 0, stream>>>(cnt, 0, N + 1);
  k_hist_dst<<<gE, 256, 0, stream>>>(dstp, cnt, E);
  k_scan_a<<<gN1, 256, 0, stream>>>(cnt, row_ptr, bsums, N + 1);
  k_scan_b<<<1, 256, 0, stream>>>(bsums, gN1);
  k_scan_c<<<gN1, 256, 0, stream>>>(row_ptr, bsums, N + 1);
  k_copy_i32<<<gN, 256, 0, stream>>>(cnt, row_ptr, N);
  k_scatter_dst<<<gE, 256, 0, stream>>>(dstp, cnt, csr_e, E);

  // edge (src_type, rel_type) buckets
  k_fill_i32<<<1, 256, 0, stream>>>(bcnt, 0, 16);
  k_bhist<<<gE, 256, 0, stream>>>(src, edge_type, node_type, bcnt, E);
  k_bscan<<<1, 64, 0, stream>>>(bcnt, bal, bcur);
  k_fill_i32<<<gEP, 256, 0, stream>>>(esorted, -1, EP);
  k_bscatter<<<gE, 256, 0, stream>>>(src, edge_type, node_type, bcur, esorted, E);

  // node type buckets
  k_fill_i32<<<1, 256, 0, stream>>>(ncnt, 0, 16);
  k_nhist<<<gN, 256, 0, stream>>>(node_type, ncnt, N);
  k_nscan<<<1, 64, 0, stream>>>(ncnt, nal, ncur);
  k_fill_i32<<<gNP, 256, 0, stream>>>(nsorted, -1, NP);
  k_nscatter<<<gN, 256, 0, stream>>>(node_type, ncur, nsorted, N);

  // f16 transposed weights
  k_transp<<<dim3(HD, T_N), 128, 0, stream>>>(adapt_W, adaptWT, IND, HD);
  for (int l = 0; l < 2; l++) {
    k_transp<<<dim3(HD, T_N), 128, 0, stream>>>(
        Wq + (size_t)l * T_N * HD * HD, WqT + (size_t)l * T_N * HD * HD, HD, HD);
    k_transp<<<dim3(HD, T_N), 128, 0, stream>>>(
        Wa + (size_t)l * T_N * HD * HD, WaT + (size_t)l * T_N * HD * HD, HD, HD);
  }

  // adapt: x = tanh(node_feature @ adapt_W[t] + adapt_b[t])
  k_ngemm<IND, 0><<<ntiles, 256, 0, stream>>>(
      node_feature, adaptWT, adapt_b, nsorted, nal, nullptr, x, nullptr);

  for (int l = 0; l < 2; l++) {
    k_rte<<<MAXT, 64, 0, stream>>>(rte_emb, rte_W, rte_b, rte_t, l);
    k_wcomb<<<12 * 256, 128, 0, stream>>>(Wk, Wv, bk, bv, rel_att, rel_msg,
                                          Wcomb, bcomb, l);
    k_ngemm<HD, 1><<<ntiles, 256, 0, stream>>>(
        x, WqT + (size_t)l * T_N * HD * HD, bq + (size_t)l * T_N * HD,
        nsorted, nal, nullptr, q_nodes, nullptr);
    k_edge_gemm<<<etiles, 256, 0, stream>>>(x, rte_t, Wcomb, bcomb, q_nodes,
                                            esorted, bal, src, dstp, edge_time,
                                            node_type,
                                            rel_pri + (size_t)l * T_N * R_N * T_N * NH,
                                            score, v_e);
    k_aggr<<<N, 64, 0, stream>>>(row_ptr, csr_e, score, v_e, q_nodes, N);
    k_ngemm<HD, 2><<<ntiles, 256, 0, stream>>>(
        q_nodes, WaT + (size_t)l * T_N * HD * HD, ba + (size_t)l * T_N * HD,
        nsorted, nal, skip + (size_t)l * T_N, x, x);
  }
}

// Round 9
// 934.328 us; speedup vs baseline: 7.8132x; 1.2328x over previous
//
#include <hip/hip_runtime.h>
#include <cstdint>
#include <cstddef>

// HGT forward (2 layers) on MI355X.
// R8b: R8's f16-gather + CSR-permuted-write design, with the workspace cut
// from ~290MB back under the (inferred 256MiB) ws limit: score stored f16,
// and q_h / g share one f16 buffer (disjoint stream-ordered lifetimes).
// Total scratch ~252 MB (< R7's proven 264.5 MB).

namespace {

constexpr int T_N  = 3;
constexpr int R_N  = 4;
constexpr int HD   = 128;
constexpr int IND  = 256;
constexpr int NH   = 8;
constexpr int MAXT = 240;

typedef unsigned short u16;
typedef unsigned int   u32;
typedef _Float16 f16;
typedef __attribute__((ext_vector_type(8))) _Float16 f16x8;
typedef __attribute__((ext_vector_type(4))) float    f32x4;

// ----------------------------- utility kernels -----------------------------
__global__ void k_fill_i32(int* __restrict__ p, int v, int n) {
  int i = blockIdx.x * 256 + threadIdx.x;
  if (i < n) p[i] = v;
}
__global__ void k_copy_i32(int* __restrict__ d, const int* __restrict__ s, int n) {
  int i = blockIdx.x * 256 + threadIdx.x;
  if (i < n) d[i] = s[i];
}
__global__ void k_hist_dst(const int* __restrict__ dst, int* __restrict__ cnt, int E) {
  int i = blockIdx.x * 256 + threadIdx.x;
  if (i < E) atomicAdd(&cnt[dst[i]], 1);
}
__global__ void k_scan_a(const int* __restrict__ in, int* __restrict__ out,
                         int* __restrict__ bsums, int n) {
  __shared__ int s[256];
  int gid = blockIdx.x * 256 + threadIdx.x;
  int v = (gid < n) ? in[gid] : 0;
  s[threadIdx.x] = v;
  __syncthreads();
  for (int off = 1; off < 256; off <<= 1) {
    int t = (threadIdx.x >= off) ? s[threadIdx.x - off] : 0;
    __syncthreads();
    s[threadIdx.x] += t;
    __syncthreads();
  }
  if (gid < n) out[gid] = s[threadIdx.x] - v;
  if (threadIdx.x == 255) bsums[blockIdx.x] = s[255];
}
__global__ void k_scan_b(int* __restrict__ bsums, int nb) {
  __shared__ int s[256];
  int v = (threadIdx.x < nb) ? bsums[threadIdx.x] : 0;
  s[threadIdx.x] = v;
  __syncthreads();
  for (int off = 1; off < 256; off <<= 1) {
    int t = (threadIdx.x >= off) ? s[threadIdx.x - off] : 0;
    __syncthreads();
    s[threadIdx.x] += t;
    __syncthreads();
  }
  if (threadIdx.x < nb) bsums[threadIdx.x] = s[threadIdx.x] - v;
}
__global__ void k_scan_c(int* __restrict__ out, const int* __restrict__ bsums, int n) {
  int gid = blockIdx.x * 256 + threadIdx.x;
  if (gid < n) out[gid] += bsums[blockIdx.x];
}
// rank[e] = position of edge e in the dst-CSR ordering
__global__ void k_rank_dst(const int* __restrict__ dst, int* __restrict__ cur,
                           int* __restrict__ rank, int E) {
  int i = blockIdx.x * 256 + threadIdx.x;
  if (i < E) rank[i] = atomicAdd(&cur[dst[i]], 1);
}
__global__ void k_bhist(const int* __restrict__ src, const int* __restrict__ etype,
                        const int* __restrict__ ntype, int* __restrict__ bcnt, int E) {
  __shared__ int loc[12];
  if (threadIdx.x < 12) loc[threadIdx.x] = 0;
  __syncthreads();
  int i = blockIdx.x * 256 + threadIdx.x;
  if (i < E) {
    int b = ntype[src[i]] * R_N + etype[i];
    atomicAdd(&loc[b], 1);
  }
  __syncthreads();
  if (threadIdx.x < 12) atomicAdd(&bcnt[threadIdx.x], loc[threadIdx.x]);
}
__global__ void k_bscan(const int* __restrict__ bcnt, int* __restrict__ bal,
                        int* __restrict__ bcur) {
  if (threadIdx.x == 0 && blockIdx.x == 0) {
    int run = 0;
    for (int b = 0; b < 12; b++) {
      bal[b] = run;
      bcur[b] = run;
      run += (bcnt[b] + 63) & ~63;
    }
    bal[12] = run;
  }
}
__global__ void k_bscatter(const int* __restrict__ src, const int* __restrict__ etype,
                           const int* __restrict__ ntype, int* __restrict__ bcur,
                           int* __restrict__ esorted, int E) {
  __shared__ int loc[12];
  __shared__ int base[12];
  if (threadIdx.x < 12) loc[threadIdx.x] = 0;
  __syncthreads();
  int i = blockIdx.x * 256 + threadIdx.x;
  int b = 0, lpos = 0;
  if (i < E) {
    b = ntype[src[i]] * R_N + etype[i];
    lpos = atomicAdd(&loc[b], 1);
  }
  __syncthreads();
  if (threadIdx.x < 12) {
    int c = loc[threadIdx.x];
    base[threadIdx.x] = (c > 0) ? atomicAdd(&bcur[threadIdx.x], c) : 0;
  }
  __syncthreads();
  if (i < E) esorted[base[b] + lpos] = i;
}
// node-type buckets (3), 64-aligned
__global__ void k_nhist(const int* __restrict__ ntype, int* __restrict__ ncnt, int N) {
  __shared__ int loc[3];
  if (threadIdx.x < 3) loc[threadIdx.x] = 0;
  __syncthreads();
  int i = blockIdx.x * 256 + threadIdx.x;
  if (i < N) atomicAdd(&loc[ntype[i]], 1);
  __syncthreads();
  if (threadIdx.x < 3) atomicAdd(&ncnt[threadIdx.x], loc[threadIdx.x]);
}
__global__ void k_nscan(const int* __restrict__ ncnt, int* __restrict__ nal,
                        int* __restrict__ ncur) {
  if (threadIdx.x == 0 && blockIdx.x == 0) {
    int run = 0;
    for (int t = 0; t < 3; t++) {
      nal[t] = run;
      ncur[t] = run;
      run += (ncnt[t] + 63) & ~63;
    }
    nal[3] = run;
  }
}
__global__ void k_nscatter(const int* __restrict__ ntype, int* __restrict__ ncur,
                           int* __restrict__ nsorted, int N) {
  __shared__ int loc[3];
  __shared__ int base[3];
  if (threadIdx.x < 3) loc[threadIdx.x] = 0;
  __syncthreads();
  int i = blockIdx.x * 256 + threadIdx.x;
  int t = 0, lpos = 0;
  if (i < N) {
    t = ntype[i];
    lpos = atomicAdd(&loc[t], 1);
  }
  __syncthreads();
  if (threadIdx.x < 3) {
    int c = loc[threadIdx.x];
    base[threadIdx.x] = (c > 0) ? atomicAdd(&ncur[threadIdx.x], c) : 0;
  }
  __syncthreads();
  if (i < N) nsorted[base[t] + lpos] = i;
}

// transpose+f16: src [T][Kd][Cd] fp32 -> dst [T][Cd][Kd] f16 (k contiguous)
__global__ void k_transp(const float* __restrict__ src, u16* __restrict__ dst,
                         int Kd, int Cd) {
  int c = blockIdx.x;
  int t = blockIdx.y;
  for (int k = threadIdx.x; k < Kd; k += blockDim.x)
    dst[((size_t)t * Cd + c) * Kd + k] =
        __builtin_bit_cast(u16, (f16)src[((size_t)t * Kd + k) * Cd + c]);
}

// ------------------------------ math kernels -------------------------------
// rte table -> f16 [240][128]
__global__ void k_rte(const float* __restrict__ emb, const float* __restrict__ W,
                      const float* __restrict__ bias, u16* __restrict__ out, int l) {
  int t = blockIdx.x;
  int lane = threadIdx.x;
  __shared__ __align__(16) float s[2 * HD];
  ((float4*)s)[lane] = ((const float4*)(emb + (size_t)t * 2 * HD))[lane];
  __syncthreads();
  const float* Wl = W + (size_t)l * 2 * HD * HD;
  float o0 = bias[l * HD + 2 * lane];
  float o1 = bias[l * HD + 2 * lane + 1];
  #pragma unroll 4
  for (int k = 0; k < 2 * HD; k++) {
    float xv = s[k];
    float2 w = ((const float2*)(Wl + (size_t)k * HD))[lane];
    o0 = fmaf(xv, w.x, o0);
    o1 = fmaf(xv, w.y, o1);
  }
  u32 pk = (u32)__builtin_bit_cast(u16, (f16)o0)
         | ((u32)__builtin_bit_cast(u16, (f16)o1) << 16);
  ((u32*)out)[t * 64 + lane] = pk;
}

// Combined per-(type,rel) matrices, f16, stored [b][c][k] (k contiguous)
__global__ void k_wcomb(const float* __restrict__ Wk, const float* __restrict__ Wv,
                        const float* __restrict__ bk, const float* __restrict__ bv,
                        const float* __restrict__ Ratt, const float* __restrict__ Rmsg,
                        u16* __restrict__ Wcomb, float* __restrict__ bcomb, int l) {
  int bc = blockIdx.x;
  int b  = bc >> 8;
  int c  = bc & 255;
  int st = b >> 2, rt = b & 3;
  int k  = threadIdx.x;
  bool isv = (c >= HD);
  int c0 = isv ? c - HD : c;
  int h  = c0 >> 4, cc = c0 & 15;
  const float* W = (isv ? Wv : Wk) + (((size_t)(l * T_N + st) * HD) + k) * HD + h * 16;
  const float* A = (isv ? Rmsg : Ratt) + (((size_t)(l * R_N + rt) * NH + h) * 16) * 16 + cc;
  float s = 0.f;
  #pragma unroll
  for (int d = 0; d < 16; d++) s = fmaf(W[d], A[d * 16], s);
  Wcomb[((size_t)b * 256 + c) * HD + k] = __builtin_bit_cast(u16, (f16)s);
  if (k == 0) {
    const float* bb = (isv ? bv : bk) + (size_t)(l * T_N + st) * HD + h * 16;
    float sb = 0.f;
    #pragma unroll
    for (int d = 0; d < 16; d++) sb = fmaf(bb[d], A[d * 16], sb);
    bcomb[b * 256 + c] = sb;
  }
}

// Generic MFMA node linear over type-sorted buckets.
// out = act( A[n][0..K) @ WT[t]^T + bias[t] ); ACT: 0 tanh, 1 none, 2 blend.
template<int K, int ACT, bool AHALF>
__global__ __launch_bounds__(256) void k_ngemm(
    const float* __restrict__ Af, const u16* __restrict__ Ah,
    const u16* __restrict__ WT, const float* __restrict__ bias,
    const int* __restrict__ nsorted, const int* __restrict__ nal,
    const float* __restrict__ skip_l,
    float* __restrict__ out_f, u16* __restrict__ out_h,
    const float* __restrict__ xin) {
  int tile0 = blockIdx.x * 64;
  if (tile0 >= nal[3]) return;
  int t = 0;
  #pragma unroll
  for (int i = 1; i < 3; i++) t += (tile0 >= nal[i]);

  __shared__ __align__(16) u16 ab[64 * K];   // f16, XOR-swizzled rows (G4)
  __shared__ int s_nid[64];
  int tid = threadIdx.x;
  int lane = tid & 63, w = tid >> 6;
  int l15 = lane & 15, l4 = lane >> 4;

  if (tid < 64) s_nid[tid] = nsorted[tile0 + tid];
  __syncthreads();

  { // stage: thread (row=tid>>2, quarter=tid&3) -> K/4 elements -> f16 LDS
    int r = tid >> 2, q4 = tid & 3;
    int nid = s_nid[r];
    char* rowp = (char*)ab + r * (2 * K);
    int sw = (r & 7) << 4;
    int base = q4 * (K / 2);               // byte base within row
    if (nid >= 0) {
      if (AHALF) {
        const f16x8* ap = (const f16x8*)(Ah + (size_t)nid * K + q4 * (K / 4));
        #pragma unroll
        for (int i = 0; i < K / 32; i++)
          *(f16x8*)(rowp + ((base + 16 * i) ^ sw)) = ap[i];
      } else {
        const float4* ap = (const float4*)(Af + (size_t)nid * K + q4 * (K / 4));
        #pragma unroll
        for (int i = 0; i < K / 32; i++) {
          float4 a = ap[2 * i], a2 = ap[2 * i + 1];
          f16x8 hv;
          hv[0] = (f16)a.x;  hv[1] = (f16)a.y;  hv[2] = (f16)a.z;  hv[3] = (f16)a.w;
          hv[4] = (f16)a2.x; hv[5] = (f16)a2.y; hv[6] = (f16)a2.z; hv[7] = (f16)a2.w;
          *(f16x8*)(rowp + ((base + 16 * i) ^ sw)) = hv;
        }
      }
    } else {
      f16x8 z;
      #pragma unroll
      for (int j = 0; j < 8; j++) z[j] = (f16)0.f;
      #pragma unroll
      for (int i = 0; i < K / 32; i++)
        *(f16x8*)(rowp + ((base + 16 * i) ^ sw)) = z;
    }
  }
  __syncthreads();

  f32x4 acc[4][2];
  #pragma unroll
  for (int ni = 0; ni < 2; ni++) {
    float bc = bias[t * HD + w * 32 + ni * 16 + l15];
    #pragma unroll
    for (int mi = 0; mi < 4; mi++) {
      acc[mi][ni][0] = bc; acc[mi][ni][1] = bc;
      acc[mi][ni][2] = bc; acc[mi][ni][3] = bc;
    }
  }
  const u16* Wt = WT + (size_t)t * HD * K;
  #pragma unroll
  for (int ks = 0; ks < K / 32; ks++) {
    int k0 = ks * 32 + 8 * l4;
    f16x8 bf[2], af[4];
    #pragma unroll
    for (int ni = 0; ni < 2; ni++)
      bf[ni] = *(const f16x8*)(Wt + (size_t)(w * 32 + ni * 16 + l15) * K + k0);
    #pragma unroll
    for (int mi = 0; mi < 4; mi++) {
      int row = mi * 16 + l15;
      af[mi] = *(const f16x8*)((const char*)ab + row * (2 * K) +
                               ((2 * k0) ^ ((row & 7) << 4)));
    }
    #pragma unroll
    for (int mi = 0; mi < 4; mi++)
      #pragma unroll
      for (int ni = 0; ni < 2; ni++)
        acc[mi][ni] = __builtin_amdgcn_mfma_f32_16x16x32_f16(af[mi], bf[ni],
                                                             acc[mi][ni], 0, 0, 0);
  }

  float alpha = 0.f;
  if (ACT == 2) alpha = 1.f / (1.f + expf(-skip_l[t]));
  #pragma unroll
  for (int mi = 0; mi < 4; mi++)
    #pragma unroll
    for (int r = 0; r < 4; r++) {
      int rowl = mi * 16 + l4 * 4 + r;
      int nid = s_nid[rowl];
      if (nid >= 0) {
        #pragma unroll
        for (int ni = 0; ni < 2; ni++) {
          int c = w * 32 + ni * 16 + l15;
          float val = acc[mi][ni][r];
          if (ACT == 0) val = tanhf(val);
          if (ACT == 2) {
            float xo = xin[(size_t)nid * HD + c];
            val = val * alpha + xo * (1.f - alpha);
          }
          if (out_f) out_f[(size_t)nid * HD + c] = val;
          if (out_h) out_h[(size_t)nid * HD + c] =
              __builtin_bit_cast(u16, (f16)val);
        }
      }
    }
}

// MFMA edge kernel, f16 gathers. Per 64-edge tile of one (st,rt) bucket:
// A = f16(x_h[src] + rte_h[time]); k'->scores (f16, CSR-perm); v'->v_csr.
__global__ __launch_bounds__(256) void k_edge_gemm(
    const u16* __restrict__ x_h, const u16* __restrict__ rte_h,
    const u16* __restrict__ Wcomb, const float* __restrict__ bcomb,
    const u16* __restrict__ q_h, const int* __restrict__ esorted,
    const int* __restrict__ bal, const int* __restrict__ src,
    const int* __restrict__ dst, const int* __restrict__ etime,
    const int* __restrict__ ntype, const int* __restrict__ rank,
    const float* __restrict__ pri_l,
    u16* __restrict__ score_h, u16* __restrict__ v_csr) {
  int tile0 = blockIdx.x * 64;
  if (tile0 >= bal[12]) return;
  int b = 0;
  #pragma unroll
  for (int i = 1; i < 12; i++) b += (tile0 >= bal[i]);
  int st = b >> 2, rt = b & 3;

  __shared__ __align__(16) u16 albuf[64 * HD];
  __shared__ int s_eid[64];
  __shared__ int s_dst[64];
  __shared__ int s_rank[64];
  int tid = threadIdx.x;
  int lane = tid & 63, w = tid >> 6;
  int l15 = lane & 15, l4 = lane >> 4;

  if (tid < 64) {
    int e = esorted[tile0 + tid];
    s_eid[tid] = e;
    s_dst[tid] = (e >= 0) ? dst[e] : 0;
    s_rank[tid] = (e >= 0) ? rank[e] : 0;
  }
  __syncthreads();

  { // stage: row=tid>>2, quarter=tid&3 (32 f16 each), all-f16 gather
    int r = tid >> 2, qq = tid & 3;
    int e = s_eid[r];
    char* rowp = (char*)albuf + r * 256;
    int sw = (r & 7) << 4;
    if (e >= 0) {
      const f16x8* xs = (const f16x8*)(x_h + (size_t)src[e] * HD + qq * 32);
      const f16x8* rp = (const f16x8*)(rte_h + (size_t)etime[e] * HD + qq * 32);
      #pragma unroll
      for (int i = 0; i < 4; i++) {
        f16x8 hv = xs[i] + rp[i];
        *(f16x8*)(rowp + ((qq * 64 + i * 16) ^ sw)) = hv;
      }
    } else {
      f16x8 z;
      #pragma unroll
      for (int j = 0; j < 8; j++) z[j] = (f16)0.f;
      #pragma unroll
      for (int i = 0; i < 4; i++)
        *(f16x8*)(rowp + ((qq * 64 + i * 16) ^ sw)) = z;
    }
  }
  __syncthreads();

  f32x4 acc[4][4];
  #pragma unroll
  for (int ni = 0; ni < 4; ni++) {
    float bc = bcomb[b * 256 + w * 64 + ni * 16 + l15];
    #pragma unroll
    for (int mi = 0; mi < 4; mi++) {
      acc[mi][ni][0] = bc; acc[mi][ni][1] = bc;
      acc[mi][ni][2] = bc; acc[mi][ni][3] = bc;
    }
  }
  const u16* Wb = Wcomb + (size_t)b * 256 * HD;
  #pragma unroll
  for (int ks = 0; ks < 4; ks++) {
    int k0 = ks * 32 + 8 * l4;
    f16x8 bf[4], af[4];
    #pragma unroll
    for (int ni = 0; ni < 4; ni++)
      bf[ni] = *(const f16x8*)(Wb + (size_t)(w * 64 + ni * 16 + l15) * HD + k0);
    #pragma unroll
    for (int mi = 0; mi < 4; mi++) {
      int row = mi * 16 + l15;
      af[mi] = *(const f16x8*)((const char*)albuf + row * 256 +
                               ((2 * k0) ^ ((row & 7) << 4)));
    }
    #pragma unroll
    for (int mi = 0; mi < 4; mi++)
      #pragma unroll
      for (int ni = 0; ni < 4; ni++)
        acc[mi][ni] = __builtin_amdgcn_mfma_f32_16x16x32_f16(af[mi], bf[ni],
                                                             acc[mi][ni], 0, 0, 0);
  }
  __syncthreads();

  if (w < 2) {       // k' -> albuf f16 (swizzled)
    #pragma unroll
    for (int mi = 0; mi < 4; mi++)
      #pragma unroll
      for (int r = 0; r < 4; r++) {
        int row = mi * 16 + l4 * 4 + r;
        char* rowp = (char*)albuf + row * 256;
        int sw = (row & 7) << 4;
        #pragma unroll
        for (int ni = 0; ni < 4; ni++) {
          int c = w * 64 + ni * 16 + l15;
          *(u16*)(rowp + ((2 * c) ^ sw)) =
              __builtin_bit_cast(u16, (f16)acc[mi][ni][r]);
        }
      }
  } else {           // v' -> v_csr[rank] f16
    int wv = w - 2;
    #pragma unroll
    for (int mi = 0; mi < 4; mi++)
      #pragma unroll
      for (int r = 0; r < 4; r++) {
        int rowl = mi * 16 + l4 * 4 + r;
        if (s_eid[rowl] >= 0) {
          u16* vp = v_csr + (size_t)s_rank[rowl] * HD + wv * 64 + l15;
          #pragma unroll
          for (int ni = 0; ni < 4; ni++)
            vp[ni * 16] = __builtin_bit_cast(u16, (f16)acc[mi][ni][r]);
        }
      }
  }
  __syncthreads();

  // scores: 512 (edge, head) tasks; q gather f16; write score_h[rank] (f16)
  #pragma unroll
  for (int s = 0; s < 2; s++) {
    int p = tid + 256 * s;
    int e = p >> 3, h = p & 7;
    if (s_eid[e] >= 0) {
      int d = s_dst[e];
      int tt = ntype[d];
      const char* rowp = (const char*)albuf + e * 256;
      int sw = (e & 7) << 4;
      f16x8 kh0 = *(const f16x8*)(rowp + ((h * 32) ^ sw));
      f16x8 kh1 = *(const f16x8*)(rowp + ((h * 32 + 16) ^ sw));
      const f16x8* qp = (const f16x8*)(q_h + (size_t)d * HD + h * 16);
      f16x8 qa = qp[0], qb = qp[1];
      float sc = 0.f;
      #pragma unroll
      for (int j = 0; j < 8; j++) sc += (float)qa[j] * (float)kh0[j];
      #pragma unroll
      for (int j = 0; j < 8; j++) sc += (float)qb[j] * (float)kh1[j];
      float pri = pri_l[((tt * R_N + rt) * T_N + st) * NH + h];
      score_h[(size_t)s_rank[e] * NH + h] =
          __builtin_bit_cast(u16, (f16)(sc * pri * 0.25f));
    }
  }
}

// Per-node (1 wave): segment softmax + weighted v-sum + exact GELU -> g (f16).
// All reads STREAMING (score_h/v_csr are CSR-permuted).
__global__ void k_aggr(const int* __restrict__ row_ptr,
                       const u16* __restrict__ score_h,
                       const u16* __restrict__ v_csr,
                       u16* __restrict__ g_h, int N) {
  int n = blockIdx.x;
  int lane = threadIdx.x;
  int start = row_ptr[n], end = row_ptr[n + 1];

  int h = lane & 7, jj = lane >> 3;
  float m = -3.0e38f;
  for (int idx = start + jj; idx < end; idx += 8)
    m = fmaxf(m, (float)__builtin_bit_cast(f16, score_h[(size_t)idx * NH + h]));
  #pragma unroll
  for (int off = 8; off < 64; off <<= 1) m = fmaxf(m, __shfl_xor(m, off));
  float z = 0.f;
  for (int idx = start + jj; idx < end; idx += 8)
    z += expf((float)__builtin_bit_cast(f16, score_h[(size_t)idx * NH + h]) - m);
  #pragma unroll
  for (int off = 8; off < 64; off <<= 1) z += __shfl_xor(z, off);

  int myh = lane >> 3;
  float md = __shfl(m, myh);
  float zd = __shfl(z, myh);
  float rz = (zd > 0.f) ? 1.f / zd : 0.f;

  float a0 = 0.f, a1 = 0.f;
  for (int idx = start; idx < end; idx++) {
    float sc = (float)__builtin_bit_cast(f16, score_h[(size_t)idx * NH + myh]);
    float wgt = expf(sc - md) * rz;
    u32 v2 = ((const u32*)(v_csr + (size_t)idx * HD))[lane];
    float v0 = (float)__builtin_bit_cast(f16, (u16)(v2 & 0xffffu));
    float v1 = (float)__builtin_bit_cast(f16, (u16)(v2 >> 16));
    a0 = fmaf(wgt, v0, a0);
    a1 = fmaf(wgt, v1, a1);
  }

  a0 = 0.5f * a0 * (1.f + erff(a0 * 0.7071067811865475f));
  a1 = 0.5f * a1 * (1.f + erff(a1 * 0.7071067811865475f));
  u32 pk = (u32)__builtin_bit_cast(u16, (f16)a0)
         | ((u32)__builtin_bit_cast(u16, (f16)a1) << 16);
  ((u32*)(g_h + (size_t)n * HD))[lane] = pk;
}

}  // namespace

extern "C" void kernel_launch(void* const* d_in, const int* in_sizes, int n_in,
                              void* d_out, int out_size, void* d_ws, size_t ws_size,
                              hipStream_t stream) {
  const float* node_feature = (const float*)d_in[0];
  const int*   node_type    = (const int*)d_in[1];
  const int*   edge_time    = (const int*)d_in[2];
  const int*   edge_type    = (const int*)d_in[3];
  const int*   edge_index   = (const int*)d_in[4];
  const float* adapt_W      = (const float*)d_in[5];
  const float* adapt_b      = (const float*)d_in[6];
  const float* Wk           = (const float*)d_in[7];
  const float* bk           = (const float*)d_in[8];
  const float* Wq           = (const float*)d_in[9];
  const float* bq           = (const float*)d_in[10];
  const float* Wv           = (const float*)d_in[11];
  const float* bv           = (const float*)d_in[12];
  const float* Wa           = (const float*)d_in[13];
  const float* ba           = (const float*)d_in[14];
  const float* rel_pri      = (const float*)d_in[15];
  const float* rel_att      = (const float*)d_in[16];
  const float* rel_msg      = (const float*)d_in[17];
  const float* skip         = (const float*)d_in[18];
  const float* rte_emb      = (const float*)d_in[19];
  const float* rte_W        = (const float*)d_in[20];
  const float* rte_b        = (const float*)d_in[21];

  const int N = in_sizes[1];
  const int E = in_sizes[2];
  const int* src  = edge_index;
  const int* dstp = edge_index + E;

  float* x = (float*)d_out;

  size_t off = 0;
  auto carve = [&](size_t bytes) -> void* {
    void* p = (char*)d_ws + off;
    off += (bytes + 255) & ~(size_t)255;
    return p;
  };
  // ~252 MB total (must stay under the ws limit; R8's 290MB crashed).
  u16*   v_csr   = (u16*)  carve((size_t)E * HD * 2);   // 204.8 MB, CSR-perm
  u16*   score_h = (u16*)  carve((size_t)E * NH * 2);   // 12.8 MB, CSR-perm
  u16*   x_h     = (u16*)  carve((size_t)N * HD * 2);   // 12.8 MB
  u16*   qg      = (u16*)  carve((size_t)N * HD * 2);   // 12.8 MB: q_h then g_h
  u16*   rte_h   = (u16*)  carve((size_t)MAXT * HD * 2);
  u16*   Wcomb   = (u16*)  carve((size_t)12 * 256 * HD * 2);
  float* bcomb   = (float*)carve((size_t)12 * 256 * 4);
  u16*   adaptWT = (u16*)  carve((size_t)T_N * HD * IND * 2);
  u16*   WqT     = (u16*)  carve((size_t)2 * T_N * HD * HD * 2);
  u16*   WaT     = (u16*)  carve((size_t)2 * T_N * HD * HD * 2);
  int*   row_ptr = (int*)  carve((size_t)(N + 1) * 4);
  int*   cnt     = (int*)  carve((size_t)(N + 1) * 4);
  int*   rank    = (int*)  carve((size_t)E * 4);
  int*   bsums   = (int*)  carve(1024 * 4);
  int*   bcnt    = (int*)  carve(16 * 4);
  int*   bal     = (int*)  carve(16 * 4);
  int*   bcur    = (int*)  carve(16 * 4);
  int*   ncnt    = (int*)  carve(16 * 4);
  int*   nal     = (int*)  carve(16 * 4);
  int*   ncur    = (int*)  carve(16 * 4);
  const int EP = E + 12 * 64;
  const int NP = N + 3 * 64;
  int*   esorted = (int*)  carve((size_t)EP * 4);
  int*   nsorted = (int*)  carve((size_t)NP * 4);
  (void)ws_size; (void)n_in; (void)out_size;

  const int gE  = (E + 255) / 256;
  const int gN1 = (N + 1 + 255) / 256;
  const int gN  = (N + 255) / 256;
  const int gEP = (EP + 255) / 256;
  const int gNP = (NP + 255) / 256;
  const int etiles = (EP + 63) / 64;
  const int ntiles = (NP + 63) / 64;

  // CSR row_ptr + rank permutation (dst order)
  k_fill_i32<<<gN1, 256, 0, stream>>>(cnt, 0, N + 1);
  k_hist_dst<<<gE, 256, 0, stream>>>(dstp, cnt, E);
  k_scan_a<<<gN1, 256, 0, stream>>>(cnt, row_ptr, bsums, N + 1);
  k_scan_b<<<1, 256, 0, stream>>>(bsums, gN1);
  k_scan_c<<<gN1, 256, 0, stream>>>(row_ptr, bsums, N + 1);
  k_copy_i32<<<gN, 256, 0, stream>>>(cnt, row_ptr, N);
  k_rank_dst<<<gE, 256, 0, stream>>>(dstp, cnt, rank, E);

  // edge (src_type, rel_type) buckets
  k_fill_i32<<<1, 256, 0, stream>>>(bcnt, 0, 16);
  k_bhist<<<gE, 256, 0, stream>>>(src, edge_type, node_type, bcnt, E);
  k_bscan<<<1, 64, 0, stream>>>(bcnt, bal, bcur);
  k_fill_i32<<<gEP, 256, 0, stream>>>(esorted, -1, EP);
  k_bscatter<<<gE, 256, 0, stream>>>(src, edge_type, node_type, bcur, esorted, E);

  // node type buckets
  k_fill_i32<<<1, 256, 0, stream>>>(ncnt, 0, 16);
  k_nhist<<<gN, 256, 0, stream>>>(node_type, ncnt, N);
  k_nscan<<<1, 64, 0, stream>>>(ncnt, nal, ncur);
  k_fill_i32<<<gNP, 256, 0, stream>>>(nsorted, -1, NP);
  k_nscatter<<<gN, 256, 0, stream>>>(node_type, ncur, nsorted, N);

  // f16 transposed weights
  k_transp<<<dim3(HD, T_N), 128, 0, stream>>>(adapt_W, adaptWT, IND, HD);
  for (int l = 0; l < 2; l++) {
    k_transp<<<dim3(HD, T_N), 128, 0, stream>>>(
        Wq + (size_t)l * T_N * HD * HD, WqT + (size_t)l * T_N * HD * HD, HD, HD);
    k_transp<<<dim3(HD, T_N), 128, 0, stream>>>(
        Wa + (size_t)l * T_N * HD * HD, WaT + (size_t)l * T_N * HD * HD, HD, HD);
  }

  // adapt: x = tanh(node_feature @ adapt_W[t] + adapt_b[t]); also x_h mirror
  k_ngemm<IND, 0, false><<<ntiles, 256, 0, stream>>>(
      node_feature, nullptr, adaptWT, adapt_b, nsorted, nal, nullptr,
      x, x_h, nullptr);

  for (int l = 0; l < 2; l++) {
    k_rte<<<MAXT, 64, 0, stream>>>(rte_emb, rte_W, rte_b, rte_h, l);
    k_wcomb<<<12 * 256, 128, 0, stream>>>(Wk, Wv, bk, bv, rel_att, rel_msg,
                                          Wcomb, bcomb, l);
    // q (f16 -> qg), input from x_h
    k_ngemm<HD, 1, true><<<ntiles, 256, 0, stream>>>(
        nullptr, x_h, WqT + (size_t)l * T_N * HD * HD, bq + (size_t)l * T_N * HD,
        nsorted, nal, nullptr, nullptr, qg, nullptr);
    k_edge_gemm<<<etiles, 256, 0, stream>>>(x_h, rte_h, Wcomb, bcomb, qg,
                                            esorted, bal, src, dstp, edge_time,
                                            node_type, rank,
                                            rel_pri + (size_t)l * T_N * R_N * T_N * NH,
                                            score_h, v_csr);
    // g (f16) overwrites qg -- q_h dead after edge_gemm (stream-ordered)
    k_aggr<<<N, 64, 0, stream>>>(row_ptr, score_h, v_csr, qg, N);
    // out-linear + skip blend; reads g (f16), writes x fp32 + x_h mirror
    k_ngemm<HD, 2, true><<<ntiles, 256, 0, stream>>>(
        nullptr, qg, WaT + (size_t)l * T_N * HD * HD, ba + (size_t)l * T_N * HD,
        nsorted, nal, skip + (size_t)l * T_N, x, x_h, x);
  }
}